// Round 2
// 5645.521 us; speedup vs baseline: 1.1882x; 1.1882x over previous
//
#include <hip/hip_runtime.h>
#include <stdint.h>
#include <math.h>

#define N_PART 8192
#define T_STEPS 1024
#define UKNOTS 130            // coarse u-knots k=0..129, u=k/128 (cubic source grid)
#define SIKNOTS 68            // sI-knots j=0..67, sI = SI_LO + j*SI_H
#define M2TOT (UKNOTS*SIKNOTS)
#define FKN 2049              // fine linear grid in u: entries c=0..2048, u=c/2048
#define SI_LO 0.49375f
#define SI_H  0.00625f
#define LOGNU 3.6862316527834183f
#define LOG8192 9.010913347279288f
#define DD2LW 5000.0f                 // lw = LOGNU - 5000*dd, dd=(V-vm)^2
#define DD2E  7213.4752044448170f     // 5000*log2(e)

// LDS-only barrier: orders ds ops without draining outstanding global stores.
// With the resampling index array in LDS, ALL in-loop barriers are lgkm-only:
// no global-memory dependence crosses any of them (vHist/sHist stores are
// write-only, distinct addresses per t, never re-read in-kernel).
#define BAR_LGKM() asm volatile("s_waitcnt lgkmcnt(0)\n\ts_barrier" ::: "memory")

// ---------------- Threefry-2x32 (exact JAX semantics) ----------------
__device__ __forceinline__ uint32_t rotl32(uint32_t x, int d){ return (x<<d)|(x>>(32-d)); }

__device__ __forceinline__ void tf2x32(uint32_t k0, uint32_t k1, uint32_t c0, uint32_t c1,
                                       uint32_t& o0, uint32_t& o1){
  uint32_t ks2 = k0 ^ k1 ^ 0x1BD11BDAu;
  uint32_t x0 = c0 + k0, x1 = c1 + k1;
  #define TFR(r) { x0 += x1; x1 = rotl32(x1, r); x1 ^= x0; }
  TFR(13) TFR(15) TFR(26) TFR(6)
  x0 += k1;  x1 += ks2 + 1u;
  TFR(17) TFR(29) TFR(16) TFR(24)
  x0 += ks2; x1 += k0 + 2u;
  TFR(13) TFR(15) TFR(26) TFR(6)
  x0 += k0;  x1 += k1 + 3u;
  TFR(17) TFR(29) TFR(16) TFR(24)
  x0 += k1;  x1 += ks2 + 4u;
  TFR(13) TFR(15) TFR(26) TFR(6)
  x0 += ks2; x1 += k0 + 5u;
  #undef TFR
  o0 = x0; o1 = x1;
}

__device__ __forceinline__ float erfinv_xla(float x){
  float w = -log1pf(-x*x);
  float p;
  if (w < 5.0f){
    w -= 2.5f;
    p = 2.81022636e-08f;
    p = fmaf(p, w, 3.43273939e-07f);
    p = fmaf(p, w, -3.5233877e-06f);
    p = fmaf(p, w, -4.39150654e-06f);
    p = fmaf(p, w, 0.00021858087f);
    p = fmaf(p, w, -0.00125372503f);
    p = fmaf(p, w, -0.00417768164f);
    p = fmaf(p, w, 0.246640727f);
    p = fmaf(p, w, 1.50140941f);
  } else {
    w = sqrtf(w) - 3.0f;
    p = -0.000200214257f;
    p = fmaf(p, w, 0.000100950558f);
    p = fmaf(p, w, 0.00134934322f);
    p = fmaf(p, w, -0.00367342844f);
    p = fmaf(p, w, 0.00573950773f);
    p = fmaf(p, w, -0.0076224613f);
    p = fmaf(p, w, 0.00943887047f);
    p = fmaf(p, w, 1.00167406f);
    p = fmaf(p, w, 2.83297682f);
  }
  return p * x;
}

// ---------------- kernel 1: per-step keys + u0 ----------------
__global__ void k_keys(uint32_t* __restrict__ knKeys, float* __restrict__ u0Tab){
  int t = blockIdx.x*blockDim.x + threadIdx.x;
  if (t >= T_STEPS) return;
  uint32_t kA0,kA1,kB0,kB1;
  tf2x32(0u,42u, 0u,0u, kA0,kA1);
  tf2x32(0u,42u, 0u,1u, kB0,kB1);
  auto splitElem = [&](uint32_t kk0, uint32_t kk1, int idx)->uint32_t{
    uint32_t o0,o1;
    if (idx < T_STEPS){ tf2x32(kk0,kk1,(uint32_t)idx,(uint32_t)(T_STEPS+idx),o0,o1); return o0; }
    int i = idx - T_STEPS;
    tf2x32(kk0,kk1,(uint32_t)i,(uint32_t)(T_STEPS+i),o0,o1); return o1;
  };
  uint32_t n0 = splitElem(kA0,kA1, 2*t);
  uint32_t n1 = splitElem(kA0,kA1, 2*t+1);
  uint32_t r0 = splitElem(kB0,kB1, 2*t);
  uint32_t r1 = splitElem(kB0,kB1, 2*t+1);
  knKeys[2*t] = n0; knKeys[2*t+1] = n1;
  uint32_t o0,o1; tf2x32(r0,r1,0u,0u,o0,o1);
  u0Tab[t] = __uint_as_float((o0>>9) | 0x3f800000u) - 1.0f;
}

// ---------------- kernel 2: noise table ----------------
__global__ void k_noise(const uint32_t* __restrict__ knKeys, float* __restrict__ noiseTab){
  int t = blockIdx.x;
  uint32_t k0 = knKeys[2*t], k1 = knKeys[2*t+1];
  const int half = N_PART/2;
  const float lo = -0.99999994f;
  for (int i = threadIdx.x; i < half; i += blockDim.x){
    uint32_t o0,o1; tf2x32(k0,k1,(uint32_t)i,(uint32_t)(half+i),o0,o1);
    float ua = __uint_as_float((o0>>9)|0x3f800000u) - 1.0f;
    float ub = __uint_as_float((o1>>9)|0x3f800000u) - 1.0f;
    float va = fmaxf(lo, ua*2.0f + lo);
    float vb = fmaxf(lo, ub*2.0f + lo);
    float na = 1.4142135623730951f * erfinv_xla(va);
    float nb = 1.4142135623730951f * erfinv_xla(vb);
    noiseTab[(size_t)t*N_PART + i]        = 0.005f * na;
    noiseTab[(size_t)t*N_PART + half + i] = 0.005f * nb;
  }
}

// ---------------- kernel 3: (u, sI)-grid MLP GEMM ----------------
__global__ __launch_bounds__(256) void k_gemm(
    const float* __restrict__ W1, const float* __restrict__ b1,
    const float* __restrict__ W2, const float* __restrict__ b2,
    const float* __restrict__ W3, float* __restrict__ Zpart)
{
  __shared__ float sA[32][64];
  __shared__ float sB[32][129];
  __shared__ float sSoc[64], sSI[64];
  __shared__ float sRed[64][17];

  const int tid = threadIdx.x;
  const int m0 = blockIdx.x * 64;
  const int n0 = blockIdx.y * 128;

  if (tid < 64){
    int r = m0 + tid; if (r >= M2TOT) r = M2TOT-1;
    int k = r / SIKNOTS;
    int j = r - k*SIKNOTS;
    float u = (float)k * (1.0f/128.0f);
    sSoc[tid] = u*u;
    sSI[tid]  = SI_LO + SI_H * (float)j;
  }
  __syncthreads();

  const int tx = tid & 15;
  const int ty = tid >> 4;
  float acc[4][8];
  #pragma unroll
  for (int i=0;i<4;i++)
    #pragma unroll
    for (int q=0;q<8;q++) acc[i][q] = 0.0f;

  for (int kc = 0; kc < 1024; kc += 32){
    {
      int base = tid*8;
      int jj = base >> 6;
      int mm = base & 63;
      int j = kc + jj;
      float w0 = W1[2*j], w1v = W1[2*j+1], bb = b1[j];
      #pragma unroll
      for (int e=0;e<8;e++){
        int m = mm + e;
        float pre = sSoc[m]*w0 + sSI[m]*w1v + bb;
        sA[jj][m] = 1.0f/(1.0f + expf(-pre));
      }
    }
    {
      int nl = tid & 127;
      int h  = tid >> 7;
      const float* src = W2 + (size_t)(n0 + nl)*1024 + kc + h*16;
      float4 v0 = *(const float4*)(src+0);
      float4 v1 = *(const float4*)(src+4);
      float4 v2 = *(const float4*)(src+8);
      float4 v3 = *(const float4*)(src+12);
      int kb = h*16;
      sB[kb+ 0][nl]=v0.x; sB[kb+ 1][nl]=v0.y; sB[kb+ 2][nl]=v0.z; sB[kb+ 3][nl]=v0.w;
      sB[kb+ 4][nl]=v1.x; sB[kb+ 5][nl]=v1.y; sB[kb+ 6][nl]=v1.z; sB[kb+ 7][nl]=v1.w;
      sB[kb+ 8][nl]=v2.x; sB[kb+ 9][nl]=v2.y; sB[kb+10][nl]=v2.z; sB[kb+11][nl]=v2.w;
      sB[kb+12][nl]=v3.x; sB[kb+13][nl]=v3.y; sB[kb+14][nl]=v3.z; sB[kb+15][nl]=v3.w;
    }
    __syncthreads();
    #pragma unroll
    for (int kk=0;kk<32;kk++){
      float a_[4], b_[8];
      #pragma unroll
      for (int i=0;i<4;i++) a_[i] = sA[kk][ty*4+i];
      #pragma unroll
      for (int q=0;q<8;q++) b_[q] = sB[kk][tx*8+q];
      #pragma unroll
      for (int i=0;i<4;i++)
        #pragma unroll
        for (int q=0;q<8;q++) acc[i][q] = fmaf(a_[i], b_[q], acc[i][q]);
    }
    __syncthreads();
  }
  float part[4] = {0.f,0.f,0.f,0.f};
  #pragma unroll
  for (int q=0;q<8;q++){
    int n = n0 + tx*8 + q;
    float bb = b2[n], w3 = W3[n];
    #pragma unroll
    for (int i=0;i<4;i++){
      float h = 1.0f/(1.0f + expf(-(acc[i][q] + bb)));
      part[i] = fmaf(w3, h, part[i]);
    }
  }
  #pragma unroll
  for (int i=0;i<4;i++) sRed[ty*4+i][tx] = part[i];
  __syncthreads();
  if (tid < 64){
    int r = m0 + tid;
    if (r < M2TOT){
      float s = 0.0f;
      #pragma unroll
      for (int x=0;x<16;x++) s += sRed[tid][x];
      Zpart[(size_t)blockIdx.y*M2TOT + r] = s;
    }
  }
}

// ---------------- kernel 4a: combine Z parts ----------------
__global__ void k_tabZ(const float* __restrict__ Zpart, const float* __restrict__ b3,
                       float* __restrict__ Z2D){
  int r = blockIdx.x*blockDim.x + threadIdx.x;
  if (r >= M2TOT) return;
  Z2D[r] = ((Zpart[r] + Zpart[M2TOT+r]) + Zpart[2*M2TOT+r]) + Zpart[3*M2TOT+r] + b3[0];
}

// ---------------- kernel 4b: per-(t,k) sI-interp + voc -> coarse G table ----------------
__global__ void k_tabG(const float* __restrict__ Z2D, const float* __restrict__ current,
                       float* __restrict__ Gtab){
  int m = blockIdx.x*blockDim.x + threadIdx.x;
  if (m >= T_STEPS*UKNOTS) return;
  int t = m / UKNOTS;
  int k = m - t*UKNOTS;
  float It = current[t];
  float sI = (It + 2.0f) * 0.25f;
  float x = (sI - SI_LO) * (1.0f/SI_H);
  int c = (int)x; if (c < 1) c = 1; if (c > 65) c = 65;
  float xi = x - (float)c;
  const float* zp = Z2D + k*SIKNOTS + (c-1);
  float y0 = zp[0], y1 = zp[1], y2 = zp[2], y3 = zp[3];
  float xm1 = xi - 1.0f, xm2 = xi - 2.0f, xp1 = xi + 1.0f;
  float w0 = -(1.0f/6.0f) * xi  * xm1 * xm2;
  float w1 =  0.5f        * xp1 * xm1 * xm2;
  float w2 = -0.5f        * xi  * xp1 * xm2;
  float w3 =  (1.0f/6.0f) * xi  * xp1 * xm1;
  float z = ((w0*y0 + w1*y1) + w2*y2) + w3*y3;
  double u = (double)k / 128.0;
  double s = u*u;
  const double vL=-1.59614486, v0=4.13646328, gam=0.63726463, alp=1.40174122, bet=2.54478965;
  double voc = vL + (v0-vL)*exp(gam*(s-1.0)) + alp*vL*(s-1.0)
             + (1.0-alp)*vL*(exp(-bet) - exp(-bet*sqrt(s)));
  Gtab[m] = (float)voc - It*z;
}

// ---------------- kernel 4c: coarse cubic -> fine scalar table ----------------
__device__ __forceinline__ float cubicEval(const float* __restrict__ g, int cf){
  float x = (float)cf * (1.0f/16.0f);
  int cc = (int)x; if (cc > 127) cc = 127;
  float xi = x - (float)cc;
  float y0 = (cc == 0) ? g[1] : g[cc-1];   // even mirror in u
  float y1 = g[cc], y2 = g[cc+1], y3 = g[cc+2];
  float xm1 = xi - 1.0f, xm2 = xi - 2.0f, xp1 = xi + 1.0f;
  float w0 = -(1.0f/6.0f) * xi  * xm1 * xm2;
  float w1 =  0.5f        * xp1 * xm1 * xm2;
  float w2 = -0.5f        * xi  * xp1 * xm2;
  float w3 =  (1.0f/6.0f) * xi  * xp1 * xm1;
  return ((w0*y0 + w1*y1) + w2*y2) + w3*y3;
}
__global__ void k_tabFine(const float* __restrict__ Gtab, float* __restrict__ TabF){
  int m = blockIdx.x*blockDim.x + threadIdx.x;
  if (m >= T_STEPS*FKN) return;
  int t = m / FKN;
  int c = m - t*FKN;
  TabF[m] = cubicEval(Gtab + t*UKNOTS, c);
}

// linear interp on scalar fine table (LDS)
__device__ __forceinline__ float interpS(const float* __restrict__ tab, float s){
  float x = sqrtf(s) * 2048.0f;
  float cf = floorf(x);
  cf = fminf(cf, 2047.0f);
  int c = (int)cf;
  float xi = x - cf;
  float y0 = tab[c], y1 = tab[c+1];
  return fmaf(xi, y1 - y0, y0);
}

// ---------------- kernel 5: sequential particle filter (single block, 1024 thr) ----------------
// Isolated change this round (resubmitted — prior bench was an infra failure):
// the resampling index array moves from global memory (idxG, L2 atomics +
// agent-scope reloads + full vmcnt(0) drain at B2) into LDS (idxL, ds_max_i32 +
// plain LDS reads). All three in-loop barriers are now lgkm-only; no
// global-memory dependence crosses any barrier. Bitwise-neutral: no FP
// computation changed, only the storage location of integer tags.
// LDS: 32K socP + 16.4K tabF + 32K idxL + 128 B = 81.2 KiB (< 160 KiB, 1 block/CU).
__global__ __launch_bounds__(1024) void k_filter(
    const float* __restrict__ soc_init, const float* __restrict__ current,
    const float* __restrict__ vmeas,   const float* __restrict__ Ecrit,
    const float* __restrict__ TabF,    const float* __restrict__ noiseTab,
    const float* __restrict__ u0Tab,
    float* __restrict__ vHist, float* __restrict__ sHist,
    long strideT, long strideP, float* __restrict__ lossOut)
{
  __shared__ __align__(16) float socP[N_PART];     // 32 KiB (exact f32 propagated state)
  __shared__ __align__(16) float tabF[2][2052];    // 16.4 KiB dbuf
  __shared__ __align__(16) int   idxL[N_PART];     // 32 KiB resample tags (was global idxG)
  __shared__ float ddW[16];
  __shared__ float sWv[16];

  const int tid = threadIdx.x;
  const int lane = tid & 63;
  const int wv = tid >> 6;
  const float ec = Ecrit[0];

  // prologue
  tabF[0][tid]      = TabF[tid];
  tabF[0][1024+tid] = TabF[1024+tid];
  if (tid == 0) tabF[0][2048] = TabF[2048];
  {
    // stale-tag init: any tag (>= 0) beats -1; tags increase monotonically with t
    int4 neg = {-1,-1,-1,-1};
    int4* ip = (int4*)&idxL[tid*8];
    ip[0] = neg; ip[1] = neg;
  }
  const float4* nzp = (const float4*)noiseTab + tid*2;
  float4 nzA = nzp[0], nzB = nzp[1];
  float soc[8], V[8];
  __syncthreads();
  #pragma unroll
  for (int k=0;k<8;k++){
    float s = soc_init[tid*8+k];
    soc[k] = s;
    V[k] = interpS(tabF[0], s);
  }
  float loss = 0.0f;
  float Iprev = current[0];

  for (int t=0; t<T_STEPS; t++){
    const int cur = t & 1, nxt = cur ^ 1;
    const int tagBase = t << 13;

    // prefetch next-step table + noise into registers
    int tn = (t+1 < T_STEPS) ? t+1 : t;
    const float* tRow = TabF + (size_t)tn * FKN;
    float pf0 = tRow[tid];
    float pf1 = tRow[1024+tid];
    float pf2 = 0.0f;
    if (tid == 0) pf2 = tRow[2048];
    const float4* nzn = (const float4*)(noiseTab + (size_t)tn*N_PART) + tid*2;
    float4 nzA2 = nzn[0], nzB2 = nzn[1];

    float It = current[t];
    float vm = vmeas[t];
    float u0 = u0Tab[t];
    float coef = -(Iprev / 26267.160775850585f) * ec;
    float nz[8] = {nzA.x,nzA.y,nzA.z,nzA.w,nzB.x,nzB.y,nzB.z,nzB.w};
    const float* tf = tabF[cur];

    // ---- phase 1: propagate + measure (socP write in LDS, exact f32) ----
    float dd[8];
    float dmin = INFINITY;
    #pragma unroll
    for (int k=0;k<8;k++){
      float s = fmaf(V[k], coef, soc[k]);
      s = s + nz[k];
      s = fminf(1.0f, fmaxf(s, 1e-10f));
      socP[tid*8+k] = s;
      float Vn = interpS(tf, s);
      V[k] = Vn;
      float d = Vn - vm;
      float q = d*d;
      dd[k] = q;
      dmin = fminf(dmin, q);
    }
    if (strideP == 1){
      float4 a = {V[0],V[1],V[2],V[3]}, b = {V[4],V[5],V[6],V[7]};
      float4* dst = (float4*)(vHist + (size_t)t*strideT + tid*8);
      dst[0] = a; dst[1] = b;
    } else {
      #pragma unroll
      for (int k=0;k<8;k++) vHist[(size_t)t*strideT + (size_t)(tid*8+k)*strideP] = V[k];
    }

    // wave min + exp prefix (wave frame)
    #pragma unroll
    for (int off=1; off<64; off<<=1) dmin = fminf(dmin, __shfl_xor(dmin, off));
    float ebase = DD2E * dmin;
    float run = 0.0f, cp[8];
    #pragma unroll
    for (int k=0;k<8;k++){
      float e = exp2f(fmaf(dd[k], -DD2E, ebase));
      run += e;
      cp[k] = run;
    }
    float sc = run;
    #pragma unroll
    for (int off=1; off<64; off<<=1){
      float o = __shfl_up(sc, (unsigned)off);
      if (lane >= off) sc += o;
    }
    float excl = __shfl_up(sc, 1);       // bitwise == prev lane's inclusive sc
    if (lane == 0) excl = 0.0f;
    if (lane == 63){ ddW[wv] = dmin; sWv[wv] = sc; }
    // commit prefetched table into the other buffer
    tabF[nxt][tid]      = pf0;
    tabF[nxt][1024+tid] = pf1;
    if (tid == 0) tabF[nxt][2048] = pf2;
    BAR_LGKM();                          // B1 (LDS-only ordering; vHist store overlaps)

    // ---- combine wave stats (lanes 0..15 of every wave, redundant; normalized frames) ----
    float baseN = 0.0f, inclN = 0.0f, scaleN = 0.0f;
    if (lane < 16){
      float dv = ddW[lane];
      float dG = dv;
      #pragma unroll
      for (int off=1; off<16; off<<=1) dG = fminf(dG, __shfl_xor(dG, off));
      float ew = exp2f(-DD2E * (dv - dG));
      float pf = sWv[lane] * ew;
      #pragma unroll
      for (int off=1; off<16; off<<=1){
        float o = __shfl_up(pf, (unsigned)off);
        if (lane >= off) pf += o;
      }
      float Sv = __shfl(pf, 15);
      float invS = 1.0f / Sv;
      float pfEx = __shfl_up(pf, 1);
      if (lane == 0) pfEx = 0.0f;
      baseN  = pfEx * invS;              // exclusive block prefix, normalized
      inclN  = pf * invS;                // inclusive; bitwise == next wave's baseN
      scaleN = ew * invS;
      if (tid == 0)
        loss = ((loss + (LOGNU - DD2LW*dG)) + logf(Sv)) - LOG8192;
    }
    float b0  = __shfl(baseN, wv);
    float bI  = __shfl(inclN, wv);
    float scl = __shfl(scaleN, wv);

    // ---- slot inversion + tagged LDS scatter (bitwise-exact seams, owners only) ----
    float scl8 = scl * 8192.0f;
    float b8   = fmaf(b0, 8192.0f, -u0);       // wave base in slot units
    float bth  = fmaf(excl, scl8, b8);
    int aPrev = __float2int_rd(bth);
    if (aPrev < -1) aPrev = -1;
    #pragma unroll
    for (int k=0;k<8;k++){
      int i = tid*8 + k;
      int a;
      if (i == N_PART-1){
        a = N_PART-1;
      } else if (k == 7){
        if (lane == 63) a = __float2int_rd(fmaf(bI, 8192.0f, -u0));  // == next wave's aPrev
        else            a = __float2int_rd(fmaf(sc, scl8, b8));      // == next thread's aPrev
        if (a > N_PART-1) a = N_PART-1;
      } else {
        a = __float2int_rd(fmaf(cp[k], scl8, bth));
        if (a > N_PART-1) a = N_PART-1;
      }
      if (a < aPrev) a = aPrev;
      int st = aPrev + 1;
      if (a >= st){                              // owners only
        int tag = tagBase + i;
        atomicMax(&idxL[st], tag);               // ds_max_i32 (LDS)
        for (int r = (st>>9)+1; (r<<9) <= a; ++r)
          atomicMax(&idxL[r<<9], tag);           // 512-region anchors
      }
      aPrev = a;
    }
    BAR_LGKM();                          // B2 (LDS-only now: ds atomics + socP ordering)

    // ---- slot phase: plain LDS idx reads, wave max-scan, LDS gather ----
    int4 q0 = *(const int4*)&idxL[tid*8+0];
    int4 q1 = *(const int4*)&idxL[tid*8+4];
    int sl[8] = { q0.x, q0.y, q0.z, q0.w, q1.x, q1.y, q1.z, q1.w };
    int pm = sl[0];
    #pragma unroll
    for (int k=1;k<8;k++) pm = max(pm, sl[k]);
    int scn = pm;
    #pragma unroll
    for (int off=1; off<64; off<<=1){
      int o = __shfl_up(scn, (unsigned)off);
      if (lane >= off) scn = max(scn, o);
    }
    int ex = __shfl_up(scn, 1);
    if (lane == 0) ex = -1;              // wave-chunk start covered by 512-anchor
    float sn[8];
    int run2 = ex;
    #pragma unroll
    for (int k=0;k<8;k++){
      run2 = max(run2, sl[k]);
      int idx = run2 - tagBase;
      if (idx < 0 || idx > N_PART-1) idx = tid*8+k;   // safety net (should not trigger)
      sn[k] = socP[idx];
    }
    if (strideP == 1){
      float4 a = {sn[0],sn[1],sn[2],sn[3]}, b = {sn[4],sn[5],sn[6],sn[7]};
      float4* dst = (float4*)(sHist + (size_t)t*strideT + tid*8);
      dst[0] = a; dst[1] = b;
    } else {
      #pragma unroll
      for (int k=0;k<8;k++) sHist[(size_t)t*strideT + (size_t)(tid*8+k)*strideP] = sn[k];
    }
    #pragma unroll
    for (int k=0;k<8;k++) soc[k] = sn[k];
    Iprev = It;
    nzA = nzA2; nzB = nzB2;
    BAR_LGKM();                          // B3 (WAR on socP + idxL; LDS-only ordering)
  }
  if (tid == 0) lossOut[0] = loss;
}

// ---------------- kernel 6: (T,N) -> (N,T) transpose ----------------
__global__ void k_transpose(const float* __restrict__ vS, const float* __restrict__ sS,
                            float* __restrict__ outV, float* __restrict__ outS){
  __shared__ float tile[32][33];
  const float* src = blockIdx.z ? sS : vS;
  float* dst = blockIdx.z ? outS : outV;
  int t0 = blockIdx.x*32, n0 = blockIdx.y*32;
  int tx = threadIdx.x, ty = threadIdx.y;
  #pragma unroll
  for (int r=0;r<4;r++)
    tile[ty+8*r][tx] = src[(size_t)(t0+ty+8*r)*N_PART + n0 + tx];
  __syncthreads();
  #pragma unroll
  for (int r=0;r<4;r++)
    dst[(size_t)(n0+ty+8*r)*T_STEPS + t0 + tx] = tile[tx][ty+8*r];
}

extern "C" void kernel_launch(void* const* d_in, const int* in_sizes, int n_in,
                              void* d_out, int out_size, void* d_ws, size_t ws_size,
                              hipStream_t stream){
  const float* soc_init = (const float*)d_in[0];
  const float* current  = (const float*)d_in[1];
  const float* vmeas    = (const float*)d_in[2];
  const float* W1 = (const float*)d_in[3];
  const float* b1 = (const float*)d_in[4];
  const float* W2 = (const float*)d_in[5];
  const float* b2 = (const float*)d_in[6];
  const float* W3 = (const float*)d_in[7];
  const float* b3 = (const float*)d_in[8];
  const float* Ec = (const float*)d_in[9];

  float* outLoss = (float*)d_out;
  float* outV = outLoss + 1;
  float* outS = outV + (size_t)N_PART*T_STEPS;

  char* p = (char*)d_ws;
  auto carve = [&](size_t bytes)->char*{ char* r = p; p += (bytes + 255) & ~(size_t)255; return r; };
  uint32_t* knKeys  = (uint32_t*)carve((size_t)2*T_STEPS*4);
  float* u0Tab      = (float*)carve((size_t)T_STEPS*4);
  float* Zpart      = (float*)carve((size_t)4*M2TOT*4);
  float* Z2D        = (float*)carve((size_t)M2TOT*4);
  float* Gtab       = (float*)carve((size_t)T_STEPS*UKNOTS*4);
  float* TabF       = (float*)carve((size_t)T_STEPS*FKN*4);
  float* noiseTab   = (float*)carve((size_t)N_PART*T_STEPS*4);
  float* vS         = (float*)carve((size_t)N_PART*T_STEPS*4);
  float* sS         = (float*)carve((size_t)N_PART*T_STEPS*4);
  bool useScratch   = ((size_t)(p - (char*)d_ws) <= ws_size);

  k_keys<<<dim3((T_STEPS+255)/256), dim3(256), 0, stream>>>(knKeys, u0Tab);
  k_noise<<<dim3(T_STEPS), dim3(256), 0, stream>>>(knKeys, noiseTab);
  k_gemm<<<dim3((M2TOT+63)/64, 4), dim3(256), 0, stream>>>(W1, b1, W2, b2, W3, Zpart);
  k_tabZ<<<dim3((M2TOT+255)/256), dim3(256), 0, stream>>>(Zpart, b3, Z2D);
  k_tabG<<<dim3((T_STEPS*UKNOTS+255)/256), dim3(256), 0, stream>>>(Z2D, current, Gtab);
  k_tabFine<<<dim3((T_STEPS*FKN+255)/256), dim3(256), 0, stream>>>(Gtab, TabF);

  if (useScratch){
    k_filter<<<dim3(1), dim3(1024), 0, stream>>>(soc_init, current, vmeas, Ec, TabF, noiseTab,
                                                 u0Tab, vS, sS, (long)N_PART, 1L, outLoss);
    k_transpose<<<dim3(T_STEPS/32, N_PART/32, 2), dim3(32,8), 0, stream>>>(vS, sS, outV, outS);
  } else {
    k_filter<<<dim3(1), dim3(1024), 0, stream>>>(soc_init, current, vmeas, Ec, TabF, noiseTab,
                                                 u0Tab, outV, outS, 1L, (long)T_STEPS, outLoss);
  }
}

// Round 3
// 5628.749 us; speedup vs baseline: 1.1918x; 1.0030x over previous
//
#include <hip/hip_runtime.h>
#include <stdint.h>
#include <math.h>

#define N_PART 8192
#define T_STEPS 1024
#define UKNOTS 130            // coarse u-knots k=0..129, u=k/128 (cubic source grid)
#define SIKNOTS 68            // sI-knots j=0..67, sI = SI_LO + j*SI_H
#define M2TOT (UKNOTS*SIKNOTS)
#define FKN 2049              // fine linear grid in u: entries c=0..2048, u=c/2048
#define SI_LO 0.49375f
#define SI_H  0.00625f
#define LOGNU 3.6862316527834183f
#define LOG8192 9.010913347279288f
#define DD2LW 5000.0f                 // lw = LOGNU - 5000*dd, dd=(V-vm)^2
#define DD2E  7213.4752044448170f     // 5000*log2(e)

// LDS-only barrier: orders ds ops without draining outstanding global stores.
// All in-loop barriers are lgkm-only: no global-memory dependence crosses any
// of them (vHist/sHist stores are write-only, never re-read in-kernel).
#define BAR_LGKM() asm volatile("s_waitcnt lgkmcnt(0)\n\ts_barrier" ::: "memory")

// ---------------- Threefry-2x32 (exact JAX semantics) ----------------
__device__ __forceinline__ uint32_t rotl32(uint32_t x, int d){ return (x<<d)|(x>>(32-d)); }

__device__ __forceinline__ void tf2x32(uint32_t k0, uint32_t k1, uint32_t c0, uint32_t c1,
                                       uint32_t& o0, uint32_t& o1){
  uint32_t ks2 = k0 ^ k1 ^ 0x1BD11BDAu;
  uint32_t x0 = c0 + k0, x1 = c1 + k1;
  #define TFR(r) { x0 += x1; x1 = rotl32(x1, r); x1 ^= x0; }
  TFR(13) TFR(15) TFR(26) TFR(6)
  x0 += k1;  x1 += ks2 + 1u;
  TFR(17) TFR(29) TFR(16) TFR(24)
  x0 += ks2; x1 += k0 + 2u;
  TFR(13) TFR(15) TFR(26) TFR(6)
  x0 += k0;  x1 += k1 + 3u;
  TFR(17) TFR(29) TFR(16) TFR(24)
  x0 += k1;  x1 += ks2 + 4u;
  TFR(13) TFR(15) TFR(26) TFR(6)
  x0 += ks2; x1 += k0 + 5u;
  #undef TFR
  o0 = x0; o1 = x1;
}

__device__ __forceinline__ float erfinv_xla(float x){
  float w = -log1pf(-x*x);
  float p;
  if (w < 5.0f){
    w -= 2.5f;
    p = 2.81022636e-08f;
    p = fmaf(p, w, 3.43273939e-07f);
    p = fmaf(p, w, -3.5233877e-06f);
    p = fmaf(p, w, -4.39150654e-06f);
    p = fmaf(p, w, 0.00021858087f);
    p = fmaf(p, w, -0.00125372503f);
    p = fmaf(p, w, -0.00417768164f);
    p = fmaf(p, w, 0.246640727f);
    p = fmaf(p, w, 1.50140941f);
  } else {
    w = sqrtf(w) - 3.0f;
    p = -0.000200214257f;
    p = fmaf(p, w, 0.000100950558f);
    p = fmaf(p, w, 0.00134934322f);
    p = fmaf(p, w, -0.00367342844f);
    p = fmaf(p, w, 0.00573950773f);
    p = fmaf(p, w, -0.0076224613f);
    p = fmaf(p, w, 0.00943887047f);
    p = fmaf(p, w, 1.00167406f);
    p = fmaf(p, w, 2.83297682f);
  }
  return p * x;
}

// ---------------- kernel 1: per-step keys + u0 ----------------
__global__ void k_keys(uint32_t* __restrict__ knKeys, float* __restrict__ u0Tab){
  int t = blockIdx.x*blockDim.x + threadIdx.x;
  if (t >= T_STEPS) return;
  uint32_t kA0,kA1,kB0,kB1;
  tf2x32(0u,42u, 0u,0u, kA0,kA1);
  tf2x32(0u,42u, 0u,1u, kB0,kB1);
  auto splitElem = [&](uint32_t kk0, uint32_t kk1, int idx)->uint32_t{
    uint32_t o0,o1;
    if (idx < T_STEPS){ tf2x32(kk0,kk1,(uint32_t)idx,(uint32_t)(T_STEPS+idx),o0,o1); return o0; }
    int i = idx - T_STEPS;
    tf2x32(kk0,kk1,(uint32_t)i,(uint32_t)(T_STEPS+i),o0,o1); return o1;
  };
  uint32_t n0 = splitElem(kA0,kA1, 2*t);
  uint32_t n1 = splitElem(kA0,kA1, 2*t+1);
  uint32_t r0 = splitElem(kB0,kB1, 2*t);
  uint32_t r1 = splitElem(kB0,kB1, 2*t+1);
  knKeys[2*t] = n0; knKeys[2*t+1] = n1;
  uint32_t o0,o1; tf2x32(r0,r1,0u,0u,o0,o1);
  u0Tab[t] = __uint_as_float((o0>>9) | 0x3f800000u) - 1.0f;
}

// ---------------- kernel 2: noise table ----------------
__global__ void k_noise(const uint32_t* __restrict__ knKeys, float* __restrict__ noiseTab){
  int t = blockIdx.x;
  uint32_t k0 = knKeys[2*t], k1 = knKeys[2*t+1];
  const int half = N_PART/2;
  const float lo = -0.99999994f;
  for (int i = threadIdx.x; i < half; i += blockDim.x){
    uint32_t o0,o1; tf2x32(k0,k1,(uint32_t)i,(uint32_t)(half+i),o0,o1);
    float ua = __uint_as_float((o0>>9)|0x3f800000u) - 1.0f;
    float ub = __uint_as_float((o1>>9)|0x3f800000u) - 1.0f;
    float va = fmaxf(lo, ua*2.0f + lo);
    float vb = fmaxf(lo, ub*2.0f + lo);
    float na = 1.4142135623730951f * erfinv_xla(va);
    float nb = 1.4142135623730951f * erfinv_xla(vb);
    noiseTab[(size_t)t*N_PART + i]        = 0.005f * na;
    noiseTab[(size_t)t*N_PART + half + i] = 0.005f * nb;
  }
}

// ---------------- kernel 3: (u, sI)-grid MLP GEMM ----------------
__global__ __launch_bounds__(256) void k_gemm(
    const float* __restrict__ W1, const float* __restrict__ b1,
    const float* __restrict__ W2, const float* __restrict__ b2,
    const float* __restrict__ W3, float* __restrict__ Zpart)
{
  __shared__ float sA[32][64];
  __shared__ float sB[32][129];
  __shared__ float sSoc[64], sSI[64];
  __shared__ float sRed[64][17];

  const int tid = threadIdx.x;
  const int m0 = blockIdx.x * 64;
  const int n0 = blockIdx.y * 128;

  if (tid < 64){
    int r = m0 + tid; if (r >= M2TOT) r = M2TOT-1;
    int k = r / SIKNOTS;
    int j = r - k*SIKNOTS;
    float u = (float)k * (1.0f/128.0f);
    sSoc[tid] = u*u;
    sSI[tid]  = SI_LO + SI_H * (float)j;
  }
  __syncthreads();

  const int tx = tid & 15;
  const int ty = tid >> 4;
  float acc[4][8];
  #pragma unroll
  for (int i=0;i<4;i++)
    #pragma unroll
    for (int q=0;q<8;q++) acc[i][q] = 0.0f;

  for (int kc = 0; kc < 1024; kc += 32){
    {
      int base = tid*8;
      int jj = base >> 6;
      int mm = base & 63;
      int j = kc + jj;
      float w0 = W1[2*j], w1v = W1[2*j+1], bb = b1[j];
      #pragma unroll
      for (int e=0;e<8;e++){
        int m = mm + e;
        float pre = sSoc[m]*w0 + sSI[m]*w1v + bb;
        sA[jj][m] = 1.0f/(1.0f + expf(-pre));
      }
    }
    {
      int nl = tid & 127;
      int h  = tid >> 7;
      const float* src = W2 + (size_t)(n0 + nl)*1024 + kc + h*16;
      float4 v0 = *(const float4*)(src+0);
      float4 v1 = *(const float4*)(src+4);
      float4 v2 = *(const float4*)(src+8);
      float4 v3 = *(const float4*)(src+12);
      int kb = h*16;
      sB[kb+ 0][nl]=v0.x; sB[kb+ 1][nl]=v0.y; sB[kb+ 2][nl]=v0.z; sB[kb+ 3][nl]=v0.w;
      sB[kb+ 4][nl]=v1.x; sB[kb+ 5][nl]=v1.y; sB[kb+ 6][nl]=v1.z; sB[kb+ 7][nl]=v1.w;
      sB[kb+ 8][nl]=v2.x; sB[kb+ 9][nl]=v2.y; sB[kb+10][nl]=v2.z; sB[kb+11][nl]=v2.w;
      sB[kb+12][nl]=v3.x; sB[kb+13][nl]=v3.y; sB[kb+14][nl]=v3.z; sB[kb+15][nl]=v3.w;
    }
    __syncthreads();
    #pragma unroll
    for (int kk=0;kk<32;kk++){
      float a_[4], b_[8];
      #pragma unroll
      for (int i=0;i<4;i++) a_[i] = sA[kk][ty*4+i];
      #pragma unroll
      for (int q=0;q<8;q++) b_[q] = sB[kk][tx*8+q];
      #pragma unroll
      for (int i=0;i<4;i++)
        #pragma unroll
        for (int q=0;q<8;q++) acc[i][q] = fmaf(a_[i], b_[q], acc[i][q]);
    }
    __syncthreads();
  }
  float part[4] = {0.f,0.f,0.f,0.f};
  #pragma unroll
  for (int q=0;q<8;q++){
    int n = n0 + tx*8 + q;
    float bb = b2[n], w3 = W3[n];
    #pragma unroll
    for (int i=0;i<4;i++){
      float h = 1.0f/(1.0f + expf(-(acc[i][q] + bb)));
      part[i] = fmaf(w3, h, part[i]);
    }
  }
  #pragma unroll
  for (int i=0;i<4;i++) sRed[ty*4+i][tx] = part[i];
  __syncthreads();
  if (tid < 64){
    int r = m0 + tid;
    if (r < M2TOT){
      float s = 0.0f;
      #pragma unroll
      for (int x=0;x<16;x++) s += sRed[tid][x];
      Zpart[(size_t)blockIdx.y*M2TOT + r] = s;
    }
  }
}

// ---------------- kernel 4a: combine Z parts ----------------
__global__ void k_tabZ(const float* __restrict__ Zpart, const float* __restrict__ b3,
                       float* __restrict__ Z2D){
  int r = blockIdx.x*blockDim.x + threadIdx.x;
  if (r >= M2TOT) return;
  Z2D[r] = ((Zpart[r] + Zpart[M2TOT+r]) + Zpart[2*M2TOT+r]) + Zpart[3*M2TOT+r] + b3[0];
}

// ---------------- kernel 4b: per-(t,k) sI-interp + voc -> coarse G table ----------------
__global__ void k_tabG(const float* __restrict__ Z2D, const float* __restrict__ current,
                       float* __restrict__ Gtab){
  int m = blockIdx.x*blockDim.x + threadIdx.x;
  if (m >= T_STEPS*UKNOTS) return;
  int t = m / UKNOTS;
  int k = m - t*UKNOTS;
  float It = current[t];
  float sI = (It + 2.0f) * 0.25f;
  float x = (sI - SI_LO) * (1.0f/SI_H);
  int c = (int)x; if (c < 1) c = 1; if (c > 65) c = 65;
  float xi = x - (float)c;
  const float* zp = Z2D + k*SIKNOTS + (c-1);
  float y0 = zp[0], y1 = zp[1], y2 = zp[2], y3 = zp[3];
  float xm1 = xi - 1.0f, xm2 = xi - 2.0f, xp1 = xi + 1.0f;
  float w0 = -(1.0f/6.0f) * xi  * xm1 * xm2;
  float w1 =  0.5f        * xp1 * xm1 * xm2;
  float w2 = -0.5f        * xi  * xp1 * xm2;
  float w3 =  (1.0f/6.0f) * xi  * xp1 * xm1;
  float z = ((w0*y0 + w1*y1) + w2*y2) + w3*y3;
  double u = (double)k / 128.0;
  double s = u*u;
  const double vL=-1.59614486, v0=4.13646328, gam=0.63726463, alp=1.40174122, bet=2.54478965;
  double voc = vL + (v0-vL)*exp(gam*(s-1.0)) + alp*vL*(s-1.0)
             + (1.0-alp)*vL*(exp(-bet) - exp(-bet*sqrt(s)));
  Gtab[m] = (float)voc - It*z;
}

// ---------------- kernel 4c: coarse cubic -> fine scalar table ----------------
__device__ __forceinline__ float cubicEval(const float* __restrict__ g, int cf){
  float x = (float)cf * (1.0f/16.0f);
  int cc = (int)x; if (cc > 127) cc = 127;
  float xi = x - (float)cc;
  float y0 = (cc == 0) ? g[1] : g[cc-1];   // even mirror in u
  float y1 = g[cc], y2 = g[cc+1], y3 = g[cc+2];
  float xm1 = xi - 1.0f, xm2 = xi - 2.0f, xp1 = xi + 1.0f;
  float w0 = -(1.0f/6.0f) * xi  * xm1 * xm2;
  float w1 =  0.5f        * xp1 * xm1 * xm2;
  float w2 = -0.5f        * xi  * xp1 * xm2;
  float w3 =  (1.0f/6.0f) * xi  * xp1 * xm1;
  return ((w0*y0 + w1*y1) + w2*y2) + w3*y3;
}
__global__ void k_tabFine(const float* __restrict__ Gtab, float* __restrict__ TabF){
  int m = blockIdx.x*blockDim.x + threadIdx.x;
  if (m >= T_STEPS*FKN) return;
  int t = m / FKN;
  int c = m - t*FKN;
  TabF[m] = cubicEval(Gtab + t*UKNOTS, c);
}

// linear interp on scalar fine table (LDS)
__device__ __forceinline__ float interpS(const float* __restrict__ tab, float s){
  float x = sqrtf(s) * 2048.0f;
  float cf = floorf(x);
  cf = fminf(cf, 2047.0f);
  int c = (int)cf;
  float xi = x - cf;
  float y0 = tab[c], y1 = tab[c+1];
  return fmaf(xi, y1 - y0, y0);
}

// ---------------- kernel 5: sequential particle filter (single block, 1024 thr) ----------------
// Isolated change this round: double-buffer socP and idxL (parity = t&1) and
// DELETE barrier B3. The WAR hazards B3 closed (phase1(t+1) overwriting socP
// while slot-phase(t) reads it; scatter(t+1) overwriting idxL while reads(t)
// pending) vanish because consecutive steps use opposite buffers; same-buffer
// write->read pairs are separated by >=1 barrier (phase1(t)->B1,B2->gather(t)).
// 2 barriers/step instead of 3, and the window {slot(t) -> gather(t) ->
// phase1(t+1) -> scans(t+1)} is barrier-free so waves drift and hide latency.
// Bitwise-identical output: no FP change, only buffer addresses alternate.
// LDS: 64K socP + 16.4K tabF + 64K idxL + 128 B = 144.2 KiB (< 160 KiB).
__global__ __launch_bounds__(1024) void k_filter(
    const float* __restrict__ soc_init, const float* __restrict__ current,
    const float* __restrict__ vmeas,   const float* __restrict__ Ecrit,
    const float* __restrict__ TabF,    const float* __restrict__ noiseTab,
    const float* __restrict__ u0Tab,
    float* __restrict__ vHist, float* __restrict__ sHist,
    long strideT, long strideP, float* __restrict__ lossOut)
{
  __shared__ __align__(16) float socP[2][N_PART];  // 64 KiB dbuf (exact f32 state)
  __shared__ __align__(16) float tabF[2][2052];    // 16.4 KiB dbuf
  __shared__ __align__(16) int   idxL[2][N_PART];  // 64 KiB dbuf resample tags
  __shared__ float ddW[16];
  __shared__ float sWv[16];

  const int tid = threadIdx.x;
  const int lane = tid & 63;
  const int wv = tid >> 6;
  const float ec = Ecrit[0];

  // prologue
  tabF[0][tid]      = TabF[tid];
  tabF[0][1024+tid] = TabF[1024+tid];
  if (tid == 0) tabF[0][2048] = TabF[2048];
  {
    // stale-tag init (both buffers): any tag (>= 0) beats -1; tags increase with t
    int4 neg = {-1,-1,-1,-1};
    int4* ip0 = (int4*)&idxL[0][tid*8];
    int4* ip1 = (int4*)&idxL[1][tid*8];
    ip0[0] = neg; ip0[1] = neg;
    ip1[0] = neg; ip1[1] = neg;
  }
  const float4* nzp = (const float4*)noiseTab + tid*2;
  float4 nzA = nzp[0], nzB = nzp[1];
  float soc[8], V[8];
  __syncthreads();
  #pragma unroll
  for (int k=0;k<8;k++){
    float s = soc_init[tid*8+k];
    soc[k] = s;
    V[k] = interpS(tabF[0], s);
  }
  float loss = 0.0f;
  float Iprev = current[0];

  for (int t=0; t<T_STEPS; t++){
    const int cur = t & 1, nxt = cur ^ 1;
    const int tagBase = t << 13;
    float* __restrict__ sp = socP[cur];
    int*   __restrict__ il = idxL[cur];

    // prefetch next-step table + noise into registers
    int tn = (t+1 < T_STEPS) ? t+1 : t;
    const float* tRow = TabF + (size_t)tn * FKN;
    float pf0 = tRow[tid];
    float pf1 = tRow[1024+tid];
    float pf2 = 0.0f;
    if (tid == 0) pf2 = tRow[2048];
    const float4* nzn = (const float4*)(noiseTab + (size_t)tn*N_PART) + tid*2;
    float4 nzA2 = nzn[0], nzB2 = nzn[1];

    float It = current[t];
    float vm = vmeas[t];
    float u0 = u0Tab[t];
    float coef = -(Iprev / 26267.160775850585f) * ec;
    float nz[8] = {nzA.x,nzA.y,nzA.z,nzA.w,nzB.x,nzB.y,nzB.z,nzB.w};
    const float* tf = tabF[cur];

    // ---- phase 1: propagate + measure (socP[cur] write in LDS, exact f32) ----
    float dd[8];
    float dmin = INFINITY;
    #pragma unroll
    for (int k=0;k<8;k++){
      float s = fmaf(V[k], coef, soc[k]);
      s = s + nz[k];
      s = fminf(1.0f, fmaxf(s, 1e-10f));
      sp[tid*8+k] = s;
      float Vn = interpS(tf, s);
      V[k] = Vn;
      float d = Vn - vm;
      float q = d*d;
      dd[k] = q;
      dmin = fminf(dmin, q);
    }
    if (strideP == 1){
      float4 a = {V[0],V[1],V[2],V[3]}, b = {V[4],V[5],V[6],V[7]};
      float4* dst = (float4*)(vHist + (size_t)t*strideT + tid*8);
      dst[0] = a; dst[1] = b;
    } else {
      #pragma unroll
      for (int k=0;k<8;k++) vHist[(size_t)t*strideT + (size_t)(tid*8+k)*strideP] = V[k];
    }

    // wave min + exp prefix (wave frame)
    #pragma unroll
    for (int off=1; off<64; off<<=1) dmin = fminf(dmin, __shfl_xor(dmin, off));
    float ebase = DD2E * dmin;
    float run = 0.0f, cp[8];
    #pragma unroll
    for (int k=0;k<8;k++){
      float e = exp2f(fmaf(dd[k], -DD2E, ebase));
      run += e;
      cp[k] = run;
    }
    float sc = run;
    #pragma unroll
    for (int off=1; off<64; off<<=1){
      float o = __shfl_up(sc, (unsigned)off);
      if (lane >= off) sc += o;
    }
    float excl = __shfl_up(sc, 1);       // bitwise == prev lane's inclusive sc
    if (lane == 0) excl = 0.0f;
    if (lane == 63){ ddW[wv] = dmin; sWv[wv] = sc; }
    // commit prefetched table into the other buffer
    tabF[nxt][tid]      = pf0;
    tabF[nxt][1024+tid] = pf1;
    if (tid == 0) tabF[nxt][2048] = pf2;
    BAR_LGKM();                          // B1 (LDS-only ordering; vHist store overlaps)

    // ---- combine wave stats (lanes 0..15 of every wave, redundant; normalized frames) ----
    float baseN = 0.0f, inclN = 0.0f, scaleN = 0.0f;
    if (lane < 16){
      float dv = ddW[lane];
      float dG = dv;
      #pragma unroll
      for (int off=1; off<16; off<<=1) dG = fminf(dG, __shfl_xor(dG, off));
      float ew = exp2f(-DD2E * (dv - dG));
      float pf = sWv[lane] * ew;
      #pragma unroll
      for (int off=1; off<16; off<<=1){
        float o = __shfl_up(pf, (unsigned)off);
        if (lane >= off) pf += o;
      }
      float Sv = __shfl(pf, 15);
      float invS = 1.0f / Sv;
      float pfEx = __shfl_up(pf, 1);
      if (lane == 0) pfEx = 0.0f;
      baseN  = pfEx * invS;              // exclusive block prefix, normalized
      inclN  = pf * invS;                // inclusive; bitwise == next wave's baseN
      scaleN = ew * invS;
      if (tid == 0)
        loss = ((loss + (LOGNU - DD2LW*dG)) + logf(Sv)) - LOG8192;
    }
    float b0  = __shfl(baseN, wv);
    float bI  = __shfl(inclN, wv);
    float scl = __shfl(scaleN, wv);

    // ---- slot inversion + tagged LDS scatter (bitwise-exact seams, owners only) ----
    float scl8 = scl * 8192.0f;
    float b8   = fmaf(b0, 8192.0f, -u0);       // wave base in slot units
    float bth  = fmaf(excl, scl8, b8);
    int aPrev = __float2int_rd(bth);
    if (aPrev < -1) aPrev = -1;
    #pragma unroll
    for (int k=0;k<8;k++){
      int i = tid*8 + k;
      int a;
      if (i == N_PART-1){
        a = N_PART-1;
      } else if (k == 7){
        if (lane == 63) a = __float2int_rd(fmaf(bI, 8192.0f, -u0));  // == next wave's aPrev
        else            a = __float2int_rd(fmaf(sc, scl8, b8));      // == next thread's aPrev
        if (a > N_PART-1) a = N_PART-1;
      } else {
        a = __float2int_rd(fmaf(cp[k], scl8, bth));
        if (a > N_PART-1) a = N_PART-1;
      }
      if (a < aPrev) a = aPrev;
      int st = aPrev + 1;
      if (a >= st){                              // owners only
        int tag = tagBase + i;
        atomicMax(&il[st], tag);                 // ds_max_i32 (LDS)
        for (int r = (st>>9)+1; (r<<9) <= a; ++r)
          atomicMax(&il[r<<9], tag);             // 512-region anchors
      }
      aPrev = a;
    }
    BAR_LGKM();                          // B2 (LDS-only: ds atomics + socP ordering)

    // ---- slot phase: plain LDS idx reads, wave max-scan, LDS gather ----
    int4 q0 = *(const int4*)&il[tid*8+0];
    int4 q1 = *(const int4*)&il[tid*8+4];
    int sl[8] = { q0.x, q0.y, q0.z, q0.w, q1.x, q1.y, q1.z, q1.w };
    int pm = sl[0];
    #pragma unroll
    for (int k=1;k<8;k++) pm = max(pm, sl[k]);
    int scn = pm;
    #pragma unroll
    for (int off=1; off<64; off<<=1){
      int o = __shfl_up(scn, (unsigned)off);
      if (lane >= off) scn = max(scn, o);
    }
    int ex = __shfl_up(scn, 1);
    if (lane == 0) ex = -1;              // wave-chunk start covered by 512-anchor
    float sn[8];
    int run2 = ex;
    #pragma unroll
    for (int k=0;k<8;k++){
      run2 = max(run2, sl[k]);
      int idx = run2 - tagBase;
      if (idx < 0 || idx > N_PART-1) idx = tid*8+k;   // safety net (should not trigger)
      sn[k] = sp[idx];
    }
    if (strideP == 1){
      float4 a = {sn[0],sn[1],sn[2],sn[3]}, b = {sn[4],sn[5],sn[6],sn[7]};
      float4* dst = (float4*)(sHist + (size_t)t*strideT + tid*8);
      dst[0] = a; dst[1] = b;
    } else {
      #pragma unroll
      for (int k=0;k<8;k++) sHist[(size_t)t*strideT + (size_t)(tid*8+k)*strideP] = sn[k];
    }
    #pragma unroll
    for (int k=0;k<8;k++) soc[k] = sn[k];
    Iprev = It;
    nzA = nzA2; nzB = nzB2;
    // no B3: next iteration writes socP[nxt]/idxL[nxt] (opposite buffers);
    // same-buffer reuse is separated by B1+B2 of the intervening step.
  }
  if (tid == 0) lossOut[0] = loss;
}

// ---------------- kernel 6: (T,N) -> (N,T) transpose ----------------
__global__ void k_transpose(const float* __restrict__ vS, const float* __restrict__ sS,
                            float* __restrict__ outV, float* __restrict__ outS){
  __shared__ float tile[32][33];
  const float* src = blockIdx.z ? sS : vS;
  float* dst = blockIdx.z ? outS : outV;
  int t0 = blockIdx.x*32, n0 = blockIdx.y*32;
  int tx = threadIdx.x, ty = threadIdx.y;
  #pragma unroll
  for (int r=0;r<4;r++)
    tile[ty+8*r][tx] = src[(size_t)(t0+ty+8*r)*N_PART + n0 + tx];
  __syncthreads();
  #pragma unroll
  for (int r=0;r<4;r++)
    dst[(size_t)(n0+ty+8*r)*T_STEPS + t0 + tx] = tile[tx][ty+8*r];
}

extern "C" void kernel_launch(void* const* d_in, const int* in_sizes, int n_in,
                              void* d_out, int out_size, void* d_ws, size_t ws_size,
                              hipStream_t stream){
  const float* soc_init = (const float*)d_in[0];
  const float* current  = (const float*)d_in[1];
  const float* vmeas    = (const float*)d_in[2];
  const float* W1 = (const float*)d_in[3];
  const float* b1 = (const float*)d_in[4];
  const float* W2 = (const float*)d_in[5];
  const float* b2 = (const float*)d_in[6];
  const float* W3 = (const float*)d_in[7];
  const float* b3 = (const float*)d_in[8];
  const float* Ec = (const float*)d_in[9];

  float* outLoss = (float*)d_out;
  float* outV = outLoss + 1;
  float* outS = outV + (size_t)N_PART*T_STEPS;

  char* p = (char*)d_ws;
  auto carve = [&](size_t bytes)->char*{ char* r = p; p += (bytes + 255) & ~(size_t)255; return r; };
  uint32_t* knKeys  = (uint32_t*)carve((size_t)2*T_STEPS*4);
  float* u0Tab      = (float*)carve((size_t)T_STEPS*4);
  float* Zpart      = (float*)carve((size_t)4*M2TOT*4);
  float* Z2D        = (float*)carve((size_t)M2TOT*4);
  float* Gtab       = (float*)carve((size_t)T_STEPS*UKNOTS*4);
  float* TabF       = (float*)carve((size_t)T_STEPS*FKN*4);
  float* noiseTab   = (float*)carve((size_t)N_PART*T_STEPS*4);
  float* vS         = (float*)carve((size_t)N_PART*T_STEPS*4);
  float* sS         = (float*)carve((size_t)N_PART*T_STEPS*4);
  bool useScratch   = ((size_t)(p - (char*)d_ws) <= ws_size);

  k_keys<<<dim3((T_STEPS+255)/256), dim3(256), 0, stream>>>(knKeys, u0Tab);
  k_noise<<<dim3(T_STEPS), dim3(256), 0, stream>>>(knKeys, noiseTab);
  k_gemm<<<dim3((M2TOT+63)/64, 4), dim3(256), 0, stream>>>(W1, b1, W2, b2, W3, Zpart);
  k_tabZ<<<dim3((M2TOT+255)/256), dim3(256), 0, stream>>>(Zpart, b3, Z2D);
  k_tabG<<<dim3((T_STEPS*UKNOTS+255)/256), dim3(256), 0, stream>>>(Z2D, current, Gtab);
  k_tabFine<<<dim3((T_STEPS*FKN+255)/256), dim3(256), 0, stream>>>(Gtab, TabF);

  if (useScratch){
    k_filter<<<dim3(1), dim3(1024), 0, stream>>>(soc_init, current, vmeas, Ec, TabF, noiseTab,
                                                 u0Tab, vS, sS, (long)N_PART, 1L, outLoss);
    k_transpose<<<dim3(T_STEPS/32, N_PART/32, 2), dim3(32,8), 0, stream>>>(vS, sS, outV, outS);
  } else {
    k_filter<<<dim3(1), dim3(1024), 0, stream>>>(soc_init, current, vmeas, Ec, TabF, noiseTab,
                                                 u0Tab, outV, outS, 1L, (long)T_STEPS, outLoss);
  }
}

// Round 4
// 5297.391 us; speedup vs baseline: 1.2663x; 1.0626x over previous
//
#include <hip/hip_runtime.h>
#include <stdint.h>
#include <math.h>

#define N_PART 8192
#define T_STEPS 1024
#define UKNOTS 130            // coarse u-knots k=0..129, u=k/128 (cubic source grid)
#define SIKNOTS 68            // sI-knots j=0..67, sI = SI_LO + j*SI_H
#define M2TOT (UKNOTS*SIKNOTS)
#define FKN 2049              // fine linear grid in u: entries c=0..2048, u=c/2048
#define SI_LO 0.49375f
#define SI_H  0.00625f
#define LOGNU 3.6862316527834183f
#define LOG8192 9.010913347279288f
#define DD2LW 5000.0f                 // lw = LOGNU - 5000*dd, dd=(V-vm)^2
#define DD2E  7213.4752044448170f     // 5000*log2(e)

// LDS-only barrier: orders ds ops without draining outstanding global stores.
#define BAR_LGKM() asm volatile("s_waitcnt lgkmcnt(0)\n\ts_barrier" ::: "memory")

// ---- DPP helpers (exact: used ONLY for min/max, which are associative) ----
// update_dpp(old=x, src=x): invalid/masked lanes keep x -> identity for min/max.
template<int CTRL, int RM>
__device__ __forceinline__ int dppi(int x){
  return __builtin_amdgcn_update_dpp(x, x, CTRL, RM, 0xf, false);
}
template<int CTRL, int RM>
__device__ __forceinline__ float dppf(float x){
  return __int_as_float(__builtin_amdgcn_update_dpp(__float_as_int(x), __float_as_int(x), CTRL, RM, 0xf, false));
}
// 64-lane inclusive max-scan: row_shr 1/2/4/8 then row_bcast15 (rows1,3) + row_bcast31 (rows2,3)
__device__ __forceinline__ int dppMaxScan64(int x){
  x = max(x, dppi<0x111,0xf>(x));
  x = max(x, dppi<0x112,0xf>(x));
  x = max(x, dppi<0x114,0xf>(x));
  x = max(x, dppi<0x118,0xf>(x));
  x = max(x, dppi<0x142,0xa>(x));
  x = max(x, dppi<0x143,0xc>(x));
  return x;
}
// 64-lane min-reduce (exact): prefix-min scan, total lands in lane 63, broadcast via readlane
__device__ __forceinline__ float dppMinAll64(float x){
  x = fminf(x, dppf<0x111,0xf>(x));
  x = fminf(x, dppf<0x112,0xf>(x));
  x = fminf(x, dppf<0x114,0xf>(x));
  x = fminf(x, dppf<0x118,0xf>(x));
  x = fminf(x, dppf<0x142,0xa>(x));
  x = fminf(x, dppf<0x143,0xc>(x));
  return __int_as_float(__builtin_amdgcn_readlane(__float_as_int(x), 63));
}

// ---------------- Threefry-2x32 (exact JAX semantics) ----------------
__device__ __forceinline__ uint32_t rotl32(uint32_t x, int d){ return (x<<d)|(x>>(32-d)); }

__device__ __forceinline__ void tf2x32(uint32_t k0, uint32_t k1, uint32_t c0, uint32_t c1,
                                       uint32_t& o0, uint32_t& o1){
  uint32_t ks2 = k0 ^ k1 ^ 0x1BD11BDAu;
  uint32_t x0 = c0 + k0, x1 = c1 + k1;
  #define TFR(r) { x0 += x1; x1 = rotl32(x1, r); x1 ^= x0; }
  TFR(13) TFR(15) TFR(26) TFR(6)
  x0 += k1;  x1 += ks2 + 1u;
  TFR(17) TFR(29) TFR(16) TFR(24)
  x0 += ks2; x1 += k0 + 2u;
  TFR(13) TFR(15) TFR(26) TFR(6)
  x0 += k0;  x1 += k1 + 3u;
  TFR(17) TFR(29) TFR(16) TFR(24)
  x0 += k1;  x1 += ks2 + 4u;
  TFR(13) TFR(15) TFR(26) TFR(6)
  x0 += ks2; x1 += k0 + 5u;
  #undef TFR
  o0 = x0; o1 = x1;
}

__device__ __forceinline__ float erfinv_xla(float x){
  float w = -log1pf(-x*x);
  float p;
  if (w < 5.0f){
    w -= 2.5f;
    p = 2.81022636e-08f;
    p = fmaf(p, w, 3.43273939e-07f);
    p = fmaf(p, w, -3.5233877e-06f);
    p = fmaf(p, w, -4.39150654e-06f);
    p = fmaf(p, w, 0.00021858087f);
    p = fmaf(p, w, -0.00125372503f);
    p = fmaf(p, w, -0.00417768164f);
    p = fmaf(p, w, 0.246640727f);
    p = fmaf(p, w, 1.50140941f);
  } else {
    w = sqrtf(w) - 3.0f;
    p = -0.000200214257f;
    p = fmaf(p, w, 0.000100950558f);
    p = fmaf(p, w, 0.00134934322f);
    p = fmaf(p, w, -0.00367342844f);
    p = fmaf(p, w, 0.00573950773f);
    p = fmaf(p, w, -0.0076224613f);
    p = fmaf(p, w, 0.00943887047f);
    p = fmaf(p, w, 1.00167406f);
    p = fmaf(p, w, 2.83297682f);
  }
  return p * x;
}

// ---------------- kernel 1: per-step keys + u0 ----------------
__global__ void k_keys(uint32_t* __restrict__ knKeys, float* __restrict__ u0Tab){
  int t = blockIdx.x*blockDim.x + threadIdx.x;
  if (t >= T_STEPS) return;
  uint32_t kA0,kA1,kB0,kB1;
  tf2x32(0u,42u, 0u,0u, kA0,kA1);
  tf2x32(0u,42u, 0u,1u, kB0,kB1);
  auto splitElem = [&](uint32_t kk0, uint32_t kk1, int idx)->uint32_t{
    uint32_t o0,o1;
    if (idx < T_STEPS){ tf2x32(kk0,kk1,(uint32_t)idx,(uint32_t)(T_STEPS+idx),o0,o1); return o0; }
    int i = idx - T_STEPS;
    tf2x32(kk0,kk1,(uint32_t)i,(uint32_t)(T_STEPS+i),o0,o1); return o1;
  };
  uint32_t n0 = splitElem(kA0,kA1, 2*t);
  uint32_t n1 = splitElem(kA0,kA1, 2*t+1);
  uint32_t r0 = splitElem(kB0,kB1, 2*t);
  uint32_t r1 = splitElem(kB0,kB1, 2*t+1);
  knKeys[2*t] = n0; knKeys[2*t+1] = n1;
  uint32_t o0,o1; tf2x32(r0,r1,0u,0u,o0,o1);
  u0Tab[t] = __uint_as_float((o0>>9) | 0x3f800000u) - 1.0f;
}

// ---------------- kernel 2: noise table ----------------
__global__ void k_noise(const uint32_t* __restrict__ knKeys, float* __restrict__ noiseTab){
  int t = blockIdx.x;
  uint32_t k0 = knKeys[2*t], k1 = knKeys[2*t+1];
  const int half = N_PART/2;
  const float lo = -0.99999994f;
  for (int i = threadIdx.x; i < half; i += blockDim.x){
    uint32_t o0,o1; tf2x32(k0,k1,(uint32_t)i,(uint32_t)(half+i),o0,o1);
    float ua = __uint_as_float((o0>>9)|0x3f800000u) - 1.0f;
    float ub = __uint_as_float((o1>>9)|0x3f800000u) - 1.0f;
    float va = fmaxf(lo, ua*2.0f + lo);
    float vb = fmaxf(lo, ub*2.0f + lo);
    float na = 1.4142135623730951f * erfinv_xla(va);
    float nb = 1.4142135623730951f * erfinv_xla(vb);
    noiseTab[(size_t)t*N_PART + i]        = 0.005f * na;
    noiseTab[(size_t)t*N_PART + half + i] = 0.005f * nb;
  }
}

// ---------------- kernel 3: (u, sI)-grid MLP GEMM ----------------
__global__ __launch_bounds__(256) void k_gemm(
    const float* __restrict__ W1, const float* __restrict__ b1,
    const float* __restrict__ W2, const float* __restrict__ b2,
    const float* __restrict__ W3, float* __restrict__ Zpart)
{
  __shared__ float sA[32][64];
  __shared__ float sB[32][129];
  __shared__ float sSoc[64], sSI[64];
  __shared__ float sRed[64][17];

  const int tid = threadIdx.x;
  const int m0 = blockIdx.x * 64;
  const int n0 = blockIdx.y * 128;

  if (tid < 64){
    int r = m0 + tid; if (r >= M2TOT) r = M2TOT-1;
    int k = r / SIKNOTS;
    int j = r - k*SIKNOTS;
    float u = (float)k * (1.0f/128.0f);
    sSoc[tid] = u*u;
    sSI[tid]  = SI_LO + SI_H * (float)j;
  }
  __syncthreads();

  const int tx = tid & 15;
  const int ty = tid >> 4;
  float acc[4][8];
  #pragma unroll
  for (int i=0;i<4;i++)
    #pragma unroll
    for (int q=0;q<8;q++) acc[i][q] = 0.0f;

  for (int kc = 0; kc < 1024; kc += 32){
    {
      int base = tid*8;
      int jj = base >> 6;
      int mm = base & 63;
      int j = kc + jj;
      float w0 = W1[2*j], w1v = W1[2*j+1], bb = b1[j];
      #pragma unroll
      for (int e=0;e<8;e++){
        int m = mm + e;
        float pre = sSoc[m]*w0 + sSI[m]*w1v + bb;
        sA[jj][m] = 1.0f/(1.0f + expf(-pre));
      }
    }
    {
      int nl = tid & 127;
      int h  = tid >> 7;
      const float* src = W2 + (size_t)(n0 + nl)*1024 + kc + h*16;
      float4 v0 = *(const float4*)(src+0);
      float4 v1 = *(const float4*)(src+4);
      float4 v2 = *(const float4*)(src+8);
      float4 v3 = *(const float4*)(src+12);
      int kb = h*16;
      sB[kb+ 0][nl]=v0.x; sB[kb+ 1][nl]=v0.y; sB[kb+ 2][nl]=v0.z; sB[kb+ 3][nl]=v0.w;
      sB[kb+ 4][nl]=v1.x; sB[kb+ 5][nl]=v1.y; sB[kb+ 6][nl]=v1.z; sB[kb+ 7][nl]=v1.w;
      sB[kb+ 8][nl]=v2.x; sB[kb+ 9][nl]=v2.y; sB[kb+10][nl]=v2.z; sB[kb+11][nl]=v2.w;
      sB[kb+12][nl]=v3.x; sB[kb+13][nl]=v3.y; sB[kb+14][nl]=v3.z; sB[kb+15][nl]=v3.w;
    }
    __syncthreads();
    #pragma unroll
    for (int kk=0;kk<32;kk++){
      float a_[4], b_[8];
      #pragma unroll
      for (int i=0;i<4;i++) a_[i] = sA[kk][ty*4+i];
      #pragma unroll
      for (int q=0;q<8;q++) b_[q] = sB[kk][tx*8+q];
      #pragma unroll
      for (int i=0;i<4;i++)
        #pragma unroll
        for (int q=0;q<8;q++) acc[i][q] = fmaf(a_[i], b_[q], acc[i][q]);
    }
    __syncthreads();
  }
  float part[4] = {0.f,0.f,0.f,0.f};
  #pragma unroll
  for (int q=0;q<8;q++){
    int n = n0 + tx*8 + q;
    float bb = b2[n], w3 = W3[n];
    #pragma unroll
    for (int i=0;i<4;i++){
      float h = 1.0f/(1.0f + expf(-(acc[i][q] + bb)));
      part[i] = fmaf(w3, h, part[i]);
    }
  }
  #pragma unroll
  for (int i=0;i<4;i++) sRed[ty*4+i][tx] = part[i];
  __syncthreads();
  if (tid < 64){
    int r = m0 + tid;
    if (r < M2TOT){
      float s = 0.0f;
      #pragma unroll
      for (int x=0;x<16;x++) s += sRed[tid][x];
      Zpart[(size_t)blockIdx.y*M2TOT + r] = s;
    }
  }
}

// ---------------- kernel 4a: combine Z parts ----------------
__global__ void k_tabZ(const float* __restrict__ Zpart, const float* __restrict__ b3,
                       float* __restrict__ Z2D){
  int r = blockIdx.x*blockDim.x + threadIdx.x;
  if (r >= M2TOT) return;
  Z2D[r] = ((Zpart[r] + Zpart[M2TOT+r]) + Zpart[2*M2TOT+r]) + Zpart[3*M2TOT+r] + b3[0];
}

// ---------------- kernel 4b: per-(t,k) sI-interp + voc -> coarse G table ----------------
__global__ void k_tabG(const float* __restrict__ Z2D, const float* __restrict__ current,
                       float* __restrict__ Gtab){
  int m = blockIdx.x*blockDim.x + threadIdx.x;
  if (m >= T_STEPS*UKNOTS) return;
  int t = m / UKNOTS;
  int k = m - t*UKNOTS;
  float It = current[t];
  float sI = (It + 2.0f) * 0.25f;
  float x = (sI - SI_LO) * (1.0f/SI_H);
  int c = (int)x; if (c < 1) c = 1; if (c > 65) c = 65;
  float xi = x - (float)c;
  const float* zp = Z2D + k*SIKNOTS + (c-1);
  float y0 = zp[0], y1 = zp[1], y2 = zp[2], y3 = zp[3];
  float xm1 = xi - 1.0f, xm2 = xi - 2.0f, xp1 = xi + 1.0f;
  float w0 = -(1.0f/6.0f) * xi  * xm1 * xm2;
  float w1 =  0.5f        * xp1 * xm1 * xm2;
  float w2 = -0.5f        * xi  * xp1 * xm2;
  float w3 =  (1.0f/6.0f) * xi  * xp1 * xm1;
  float z = ((w0*y0 + w1*y1) + w2*y2) + w3*y3;
  double u = (double)k / 128.0;
  double s = u*u;
  const double vL=-1.59614486, v0=4.13646328, gam=0.63726463, alp=1.40174122, bet=2.54478965;
  double voc = vL + (v0-vL)*exp(gam*(s-1.0)) + alp*vL*(s-1.0)
             + (1.0-alp)*vL*(exp(-bet) - exp(-bet*sqrt(s)));
  Gtab[m] = (float)voc - It*z;
}

// ---------------- kernel 4c: coarse cubic -> fine scalar table ----------------
__device__ __forceinline__ float cubicEval(const float* __restrict__ g, int cf){
  float x = (float)cf * (1.0f/16.0f);
  int cc = (int)x; if (cc > 127) cc = 127;
  float xi = x - (float)cc;
  float y0 = (cc == 0) ? g[1] : g[cc-1];   // even mirror in u
  float y1 = g[cc], y2 = g[cc+1], y3 = g[cc+2];
  float xm1 = xi - 1.0f, xm2 = xi - 2.0f, xp1 = xi + 1.0f;
  float w0 = -(1.0f/6.0f) * xi  * xm1 * xm2;
  float w1 =  0.5f        * xp1 * xm1 * xm2;
  float w2 = -0.5f        * xi  * xp1 * xm2;
  float w3 =  (1.0f/6.0f) * xi  * xp1 * xm1;
  return ((w0*y0 + w1*y1) + w2*y2) + w3*y3;
}
__global__ void k_tabFine(const float* __restrict__ Gtab, float* __restrict__ TabF){
  int m = blockIdx.x*blockDim.x + threadIdx.x;
  if (m >= T_STEPS*FKN) return;
  int t = m / FKN;
  int c = m - t*FKN;
  TabF[m] = cubicEval(Gtab + t*UKNOTS, c);
}

// linear interp on scalar fine table (LDS)
__device__ __forceinline__ float interpS(const float* __restrict__ tab, float s){
  float x = sqrtf(s) * 2048.0f;
  float cf = floorf(x);
  cf = fminf(cf, 2047.0f);
  int c = (int)cf;
  float xi = x - cf;
  float y0 = tab[c], y1 = tab[c+1];
  return fmaf(xi, y1 - y0, y0);
}

// ---------------- kernel 5: sequential particle filter (single block, 1024 thr) ----------------
// Isolated changes this round (all EXACT — min/max associativity or layout only):
//  1. 64-lane dmin reduce and slot max-scan via DPP (row_shr + row_bcast) instead
//     of 6-deep ds_permute shuffle chains (~5cyc vs ~35cyc per dependent step).
//  2. Kogge-Stone (depth 3) register prefix-max replaces 8-deep serial max chains
//     in scatter (aPrev) and slot fill (run2).
//  3. dmin 8-element fold tree-ified (fmin associative, exact).
//  4. socP stores vectorized to 2x ds_write_b128 (split phase-1 loop).
//  5. tabF commit moved after B1 (drains during combine window; read is 2 barriers later).
// Float sum-scan + combine scans unchanged (association-sensitive -> bitwise-identical output).
__global__ __launch_bounds__(1024) void k_filter(
    const float* __restrict__ soc_init, const float* __restrict__ current,
    const float* __restrict__ vmeas,   const float* __restrict__ Ecrit,
    const float* __restrict__ TabF,    const float* __restrict__ noiseTab,
    const float* __restrict__ u0Tab,
    float* __restrict__ vHist, float* __restrict__ sHist,
    long strideT, long strideP, float* __restrict__ lossOut)
{
  __shared__ __align__(16) float socP[2][N_PART];  // 64 KiB dbuf (exact f32 state)
  __shared__ __align__(16) float tabF[2][2052];    // 16.4 KiB dbuf
  __shared__ __align__(16) int   idxL[2][N_PART];  // 64 KiB dbuf resample tags
  __shared__ float ddW[16];
  __shared__ float sWv[16];

  const int tid = threadIdx.x;
  const int lane = tid & 63;
  const int wv = tid >> 6;
  const float ec = Ecrit[0];

  // prologue
  tabF[0][tid]      = TabF[tid];
  tabF[0][1024+tid] = TabF[1024+tid];
  if (tid == 0) tabF[0][2048] = TabF[2048];
  {
    int4 neg = {-1,-1,-1,-1};
    int4* ip0 = (int4*)&idxL[0][tid*8];
    int4* ip1 = (int4*)&idxL[1][tid*8];
    ip0[0] = neg; ip0[1] = neg;
    ip1[0] = neg; ip1[1] = neg;
  }
  const float4* nzp = (const float4*)noiseTab + tid*2;
  float4 nzA = nzp[0], nzB = nzp[1];
  float soc[8], V[8];
  __syncthreads();
  #pragma unroll
  for (int k=0;k<8;k++){
    float s = soc_init[tid*8+k];
    soc[k] = s;
    V[k] = interpS(tabF[0], s);
  }
  float loss = 0.0f;
  float Iprev = current[0];

  for (int t=0; t<T_STEPS; t++){
    const int cur = t & 1, nxt = cur ^ 1;
    const int tagBase = t << 13;
    float* __restrict__ sp = socP[cur];
    int*   __restrict__ il = idxL[cur];

    // prefetch next-step table + noise into registers
    int tn = (t+1 < T_STEPS) ? t+1 : t;
    const float* tRow = TabF + (size_t)tn * FKN;
    float pf0 = tRow[tid];
    float pf1 = tRow[1024+tid];
    float pf2 = 0.0f;
    if (tid == 0) pf2 = tRow[2048];
    const float4* nzn = (const float4*)(noiseTab + (size_t)tn*N_PART) + tid*2;
    float4 nzA2 = nzn[0], nzB2 = nzn[1];

    float It = current[t];
    float vm = vmeas[t];
    float u0 = u0Tab[t];
    float coef = -(Iprev / 26267.160775850585f) * ec;
    float nz[8] = {nzA.x,nzA.y,nzA.z,nzA.w,nzB.x,nzB.y,nzB.z,nzB.w};
    const float* tf = tabF[cur];

    // ---- phase 1: propagate (vectorized socP store), then measure ----
    float s8[8];
    #pragma unroll
    for (int k=0;k<8;k++){
      float s = fmaf(V[k], coef, soc[k]);
      s = s + nz[k];
      s = fminf(1.0f, fmaxf(s, 1e-10f));
      s8[k] = s;
    }
    {
      float4 a = {s8[0],s8[1],s8[2],s8[3]}, b = {s8[4],s8[5],s8[6],s8[7]};
      float4* dst = (float4*)&sp[tid*8];
      dst[0] = a; dst[1] = b;
    }
    float dd[8];
    #pragma unroll
    for (int k=0;k<8;k++){
      float Vn = interpS(tf, s8[k]);
      V[k] = Vn;
      float d = Vn - vm;
      dd[k] = d*d;
    }
    if (strideP == 1){
      float4 a = {V[0],V[1],V[2],V[3]}, b = {V[4],V[5],V[6],V[7]};
      float4* dst = (float4*)(vHist + (size_t)t*strideT + tid*8);
      dst[0] = a; dst[1] = b;
    } else {
      #pragma unroll
      for (int k=0;k<8;k++) vHist[(size_t)t*strideT + (size_t)(tid*8+k)*strideP] = V[k];
    }

    // per-thread min fold (tree, exact) then 64-lane min via DPP (exact)
    float m01 = fminf(dd[0],dd[1]), m23 = fminf(dd[2],dd[3]);
    float m45 = fminf(dd[4],dd[5]), m67 = fminf(dd[6],dd[7]);
    float dmin = fminf(fminf(m01,m23), fminf(m45,m67));
    dmin = dppMinAll64(dmin);

    // exp prefix (wave frame; order-preserving)
    float ebase = DD2E * dmin;
    float run = 0.0f, cp[8];
    #pragma unroll
    for (int k=0;k<8;k++){
      float e = exp2f(fmaf(dd[k], -DD2E, ebase));
      run += e;
      cp[k] = run;
    }
    float sc = run;
    #pragma unroll
    for (int off=1; off<64; off<<=1){
      float o = __shfl_up(sc, (unsigned)off);
      if (lane >= off) sc += o;
    }
    float excl = __shfl_up(sc, 1);       // bitwise == prev lane's inclusive sc
    if (lane == 0) excl = 0.0f;
    if (lane == 63){ ddW[wv] = dmin; sWv[wv] = sc; }
    BAR_LGKM();                          // B1 (LDS-only ordering; vHist store overlaps)

    // commit prefetched table into the other buffer (drains during combine; read after B2(t)->phase1(t+1))
    tabF[nxt][tid]      = pf0;
    tabF[nxt][1024+tid] = pf1;
    if (tid == 0) tabF[nxt][2048] = pf2;

    // ---- combine wave stats (lanes 0..15 of every wave, redundant; normalized frames) ----
    float baseN = 0.0f, inclN = 0.0f, scaleN = 0.0f;
    if (lane < 16){
      float dv = ddW[lane];
      float dG = dv;
      #pragma unroll
      for (int off=1; off<16; off<<=1) dG = fminf(dG, __shfl_xor(dG, off));
      float ew = exp2f(-DD2E * (dv - dG));
      float pf = sWv[lane] * ew;
      #pragma unroll
      for (int off=1; off<16; off<<=1){
        float o = __shfl_up(pf, (unsigned)off);
        if (lane >= off) pf += o;
      }
      float Sv = __shfl(pf, 15);
      float invS = 1.0f / Sv;
      float pfEx = __shfl_up(pf, 1);
      if (lane == 0) pfEx = 0.0f;
      baseN  = pfEx * invS;              // exclusive block prefix, normalized
      inclN  = pf * invS;                // inclusive; bitwise == next wave's baseN
      scaleN = ew * invS;
      if (tid == 0)
        loss = ((loss + (LOGNU - DD2LW*dG)) + logf(Sv)) - LOG8192;
    }
    float b0  = __shfl(baseN, wv);
    float bI  = __shfl(inclN, wv);
    float scl = __shfl(scaleN, wv);

    // ---- slot inversion + tagged LDS scatter (bitwise-exact seams, owners only) ----
    float scl8 = scl * 8192.0f;
    float b8   = fmaf(b0, 8192.0f, -u0);       // wave base in slot units
    float bth  = fmaf(excl, scl8, b8);
    int aP0 = __float2int_rd(bth);
    if (aP0 < -1) aP0 = -1;
    int raw[8];
    #pragma unroll
    for (int k=0;k<7;k++){
      int a = __float2int_rd(fmaf(cp[k], scl8, bth));
      raw[k] = (a > N_PART-1) ? N_PART-1 : a;
    }
    {
      int a;
      if (tid*8+7 == N_PART-1){
        a = N_PART-1;
      } else {
        if (lane == 63) a = __float2int_rd(fmaf(bI, 8192.0f, -u0));  // == next wave's base
        else            a = __float2int_rd(fmaf(sc, scl8, b8));      // == next thread's base
        if (a > N_PART-1) a = N_PART-1;
      }
      raw[7] = a;
    }
    // prefix-max over raw (Kogge-Stone depth 3, exact == serial max chain)
    int c1[8], c2[8], c4[8];
    c1[0]=raw[0];
    #pragma unroll
    for (int k=1;k<8;k++) c1[k] = max(raw[k], raw[k-1]);
    c2[0]=c1[0]; c2[1]=c1[1];
    #pragma unroll
    for (int k=2;k<8;k++) c2[k] = max(c1[k], c1[k-2]);
    #pragma unroll
    for (int k=0;k<4;k++) c4[k] = c2[k];
    #pragma unroll
    for (int k=4;k<8;k++) c4[k] = max(c2[k], c2[k-4]);
    #pragma unroll
    for (int k=0;k<8;k++){
      int aprev = (k==0) ? aP0 : max(aP0, c4[k-1]);
      int a     = max(aP0, c4[k]);
      int st = aprev + 1;
      if (a >= st){                              // owners only
        int tag = tagBase + tid*8 + k;
        atomicMax(&il[st], tag);                 // ds_max (LDS)
        for (int r = (st>>9)+1; (r<<9) <= a; ++r)
          atomicMax(&il[r<<9], tag);             // 512-region anchors
      }
    }
    BAR_LGKM();                          // B2 (LDS-only: ds atomics + socP ordering)

    // ---- slot phase: b128 idx reads, register prefix-max, DPP wave max-scan, gather ----
    int4 q0 = *(const int4*)&il[tid*8+0];
    int4 q1 = *(const int4*)&il[tid*8+4];
    int sl[8] = { q0.x, q0.y, q0.z, q0.w, q1.x, q1.y, q1.z, q1.w };
    int d1[8], d2[8], d4[8];
    d1[0]=sl[0];
    #pragma unroll
    for (int k=1;k<8;k++) d1[k] = max(sl[k], sl[k-1]);
    d2[0]=d1[0]; d2[1]=d1[1];
    #pragma unroll
    for (int k=2;k<8;k++) d2[k] = max(d1[k], d1[k-2]);
    #pragma unroll
    for (int k=0;k<4;k++) d4[k] = d2[k];
    #pragma unroll
    for (int k=4;k<8;k++) d4[k] = max(d2[k], d2[k-4]);   // d4[k] = prefix-max sl[0..k]
    int scn = dppMaxScan64(d4[7]);       // inclusive across 64 lanes (exact)
    int ex = __shfl_up(scn, 1);
    if (lane == 0) ex = -1;              // wave-chunk start covered by 512-anchor
    float sn[8];
    #pragma unroll
    for (int k=0;k<8;k++){
      int run2 = max(ex, d4[k]);
      int idx = run2 - tagBase;
      if (idx < 0 || idx > N_PART-1) idx = tid*8+k;   // safety net (should not trigger)
      sn[k] = sp[idx];
    }
    if (strideP == 1){
      float4 a = {sn[0],sn[1],sn[2],sn[3]}, b = {sn[4],sn[5],sn[6],sn[7]};
      float4* dst = (float4*)(sHist + (size_t)t*strideT + tid*8);
      dst[0] = a; dst[1] = b;
    } else {
      #pragma unroll
      for (int k=0;k<8;k++) sHist[(size_t)t*strideT + (size_t)(tid*8+k)*strideP] = sn[k];
    }
    #pragma unroll
    for (int k=0;k<8;k++) soc[k] = sn[k];
    Iprev = It;
    nzA = nzA2; nzB = nzB2;
    // no B3: next step writes socP[nxt]/idxL[nxt]; same-buffer reuse separated by B1+B2.
  }
  if (tid == 0) lossOut[0] = loss;
}

// ---------------- kernel 6: (T,N) -> (N,T) transpose ----------------
__global__ void k_transpose(const float* __restrict__ vS, const float* __restrict__ sS,
                            float* __restrict__ outV, float* __restrict__ outS){
  __shared__ float tile[32][33];
  const float* src = blockIdx.z ? sS : vS;
  float* dst = blockIdx.z ? outS : outV;
  int t0 = blockIdx.x*32, n0 = blockIdx.y*32;
  int tx = threadIdx.x, ty = threadIdx.y;
  #pragma unroll
  for (int r=0;r<4;r++)
    tile[ty+8*r][tx] = src[(size_t)(t0+ty+8*r)*N_PART + n0 + tx];
  __syncthreads();
  #pragma unroll
  for (int r=0;r<4;r++)
    dst[(size_t)(n0+ty+8*r)*T_STEPS + t0 + tx] = tile[tx][ty+8*r];
}

extern "C" void kernel_launch(void* const* d_in, const int* in_sizes, int n_in,
                              void* d_out, int out_size, void* d_ws, size_t ws_size,
                              hipStream_t stream){
  const float* soc_init = (const float*)d_in[0];
  const float* current  = (const float*)d_in[1];
  const float* vmeas    = (const float*)d_in[2];
  const float* W1 = (const float*)d_in[3];
  const float* b1 = (const float*)d_in[4];
  const float* W2 = (const float*)d_in[5];
  const float* b2 = (const float*)d_in[6];
  const float* W3 = (const float*)d_in[7];
  const float* b3 = (const float*)d_in[8];
  const float* Ec = (const float*)d_in[9];

  float* outLoss = (float*)d_out;
  float* outV = outLoss + 1;
  float* outS = outV + (size_t)N_PART*T_STEPS;

  char* p = (char*)d_ws;
  auto carve = [&](size_t bytes)->char*{ char* r = p; p += (bytes + 255) & ~(size_t)255; return r; };
  uint32_t* knKeys  = (uint32_t*)carve((size_t)2*T_STEPS*4);
  float* u0Tab      = (float*)carve((size_t)T_STEPS*4);
  float* Zpart      = (float*)carve((size_t)4*M2TOT*4);
  float* Z2D        = (float*)carve((size_t)M2TOT*4);
  float* Gtab       = (float*)carve((size_t)T_STEPS*UKNOTS*4);
  float* TabF       = (float*)carve((size_t)T_STEPS*FKN*4);
  float* noiseTab   = (float*)carve((size_t)N_PART*T_STEPS*4);
  float* vS         = (float*)carve((size_t)N_PART*T_STEPS*4);
  float* sS         = (float*)carve((size_t)N_PART*T_STEPS*4);
  bool useScratch   = ((size_t)(p - (char*)d_ws) <= ws_size);

  k_keys<<<dim3((T_STEPS+255)/256), dim3(256), 0, stream>>>(knKeys, u0Tab);
  k_noise<<<dim3(T_STEPS), dim3(256), 0, stream>>>(knKeys, noiseTab);
  k_gemm<<<dim3((M2TOT+63)/64, 4), dim3(256), 0, stream>>>(W1, b1, W2, b2, W3, Zpart);
  k_tabZ<<<dim3((M2TOT+255)/256), dim3(256), 0, stream>>>(Zpart, b3, Z2D);
  k_tabG<<<dim3((T_STEPS*UKNOTS+255)/256), dim3(256), 0, stream>>>(Z2D, current, Gtab);
  k_tabFine<<<dim3((T_STEPS*FKN+255)/256), dim3(256), 0, stream>>>(Gtab, TabF);

  if (useScratch){
    k_filter<<<dim3(1), dim3(1024), 0, stream>>>(soc_init, current, vmeas, Ec, TabF, noiseTab,
                                                 u0Tab, vS, sS, (long)N_PART, 1L, outLoss);
    k_transpose<<<dim3(T_STEPS/32, N_PART/32, 2), dim3(32,8), 0, stream>>>(vS, sS, outV, outS);
  } else {
    k_filter<<<dim3(1), dim3(1024), 0, stream>>>(soc_init, current, vmeas, Ec, TabF, noiseTab,
                                                 u0Tab, outV, outS, 1L, (long)T_STEPS, outLoss);
  }
}

// Round 5
// 5058.659 us; speedup vs baseline: 1.3261x; 1.0472x over previous
//
#include <hip/hip_runtime.h>
#include <stdint.h>
#include <math.h>

#define N_PART 8192
#define T_STEPS 1024
#define UKNOTS 130            // coarse u-knots k=0..129, u=k/128 (cubic source grid)
#define SIKNOTS 68            // sI-knots j=0..67, sI = SI_LO + j*SI_H
#define M2TOT (UKNOTS*SIKNOTS)
#define FKN 2049              // fine linear grid in u: entries c=0..2048, u=c/2048
#define SI_LO 0.49375f
#define SI_H  0.00625f
#define LOGNU 3.6862316527834183f
#define LOG8192 9.010913347279288f
#define DD2LW 5000.0f                 // lw = LOGNU - 5000*dd, dd=(V-vm)^2
#define DD2E  7213.4752044448170f     // 5000*log2(e)

// LDS-only barrier: orders ds ops without draining outstanding global stores.
#define BAR_LGKM() asm volatile("s_waitcnt lgkmcnt(0)\n\ts_barrier" ::: "memory")

// ---- DPP helpers ----
// old=x, bound_ctrl=false: invalid lanes keep x -> identity for min/max.
template<int CTRL, int RM>
__device__ __forceinline__ int dppi(int x){
  return __builtin_amdgcn_update_dpp(x, x, CTRL, RM, 0xf, false);
}
template<int CTRL, int RM>
__device__ __forceinline__ float dppf(float x){
  return __int_as_float(__builtin_amdgcn_update_dpp(__float_as_int(x), __float_as_int(x), CTRL, RM, 0xf, false));
}
// bound_ctrl=true: invalid lanes produce 0.0f -> "+0" identity for the float scan
// (operands for valid lanes are bitwise-identical to __shfl_up Kogge-Stone).
template<int CTRL>
__device__ __forceinline__ float dppzf(float x){
  return __int_as_float(__builtin_amdgcn_update_dpp(0, __float_as_int(x), CTRL, 0xf, 0xf, true));
}
__device__ __forceinline__ float rdlanef(float x, int l){
  return __int_as_float(__builtin_amdgcn_readlane(__float_as_int(x), l));
}
// 64-lane inclusive max-scan: row_shr 1/2/4/8 then row_bcast15 (rows1,3) + row_bcast31 (rows2,3)
__device__ __forceinline__ int dppMaxScan64(int x){
  x = max(x, dppi<0x111,0xf>(x));
  x = max(x, dppi<0x112,0xf>(x));
  x = max(x, dppi<0x114,0xf>(x));
  x = max(x, dppi<0x118,0xf>(x));
  x = max(x, dppi<0x142,0xa>(x));
  x = max(x, dppi<0x143,0xc>(x));
  return x;
}
// 64-lane min-reduce (exact): prefix-min scan, total lands in lane 63, broadcast via readlane
__device__ __forceinline__ float dppMinAll64(float x){
  x = fminf(x, dppf<0x111,0xf>(x));
  x = fminf(x, dppf<0x112,0xf>(x));
  x = fminf(x, dppf<0x114,0xf>(x));
  x = fminf(x, dppf<0x118,0xf>(x));
  x = fminf(x, dppf<0x142,0xa>(x));
  x = fminf(x, dppf<0x143,0xc>(x));
  return __int_as_float(__builtin_amdgcn_readlane(__float_as_int(x), 63));
}

// ---------------- Threefry-2x32 (exact JAX semantics) ----------------
__device__ __forceinline__ uint32_t rotl32(uint32_t x, int d){ return (x<<d)|(x>>(32-d)); }

__device__ __forceinline__ void tf2x32(uint32_t k0, uint32_t k1, uint32_t c0, uint32_t c1,
                                       uint32_t& o0, uint32_t& o1){
  uint32_t ks2 = k0 ^ k1 ^ 0x1BD11BDAu;
  uint32_t x0 = c0 + k0, x1 = c1 + k1;
  #define TFR(r) { x0 += x1; x1 = rotl32(x1, r); x1 ^= x0; }
  TFR(13) TFR(15) TFR(26) TFR(6)
  x0 += k1;  x1 += ks2 + 1u;
  TFR(17) TFR(29) TFR(16) TFR(24)
  x0 += ks2; x1 += k0 + 2u;
  TFR(13) TFR(15) TFR(26) TFR(6)
  x0 += k0;  x1 += k1 + 3u;
  TFR(17) TFR(29) TFR(16) TFR(24)
  x0 += k1;  x1 += ks2 + 4u;
  TFR(13) TFR(15) TFR(26) TFR(6)
  x0 += ks2; x1 += k0 + 5u;
  #undef TFR
  o0 = x0; o1 = x1;
}

__device__ __forceinline__ float erfinv_xla(float x){
  float w = -log1pf(-x*x);
  float p;
  if (w < 5.0f){
    w -= 2.5f;
    p = 2.81022636e-08f;
    p = fmaf(p, w, 3.43273939e-07f);
    p = fmaf(p, w, -3.5233877e-06f);
    p = fmaf(p, w, -4.39150654e-06f);
    p = fmaf(p, w, 0.00021858087f);
    p = fmaf(p, w, -0.00125372503f);
    p = fmaf(p, w, -0.00417768164f);
    p = fmaf(p, w, 0.246640727f);
    p = fmaf(p, w, 1.50140941f);
  } else {
    w = sqrtf(w) - 3.0f;
    p = -0.000200214257f;
    p = fmaf(p, w, 0.000100950558f);
    p = fmaf(p, w, 0.00134934322f);
    p = fmaf(p, w, -0.00367342844f);
    p = fmaf(p, w, 0.00573950773f);
    p = fmaf(p, w, -0.0076224613f);
    p = fmaf(p, w, 0.00943887047f);
    p = fmaf(p, w, 1.00167406f);
    p = fmaf(p, w, 2.83297682f);
  }
  return p * x;
}

// ---------------- kernel 1: per-step keys + u0 ----------------
__global__ void k_keys(uint32_t* __restrict__ knKeys, float* __restrict__ u0Tab){
  int t = blockIdx.x*blockDim.x + threadIdx.x;
  if (t >= T_STEPS) return;
  uint32_t kA0,kA1,kB0,kB1;
  tf2x32(0u,42u, 0u,0u, kA0,kA1);
  tf2x32(0u,42u, 0u,1u, kB0,kB1);
  auto splitElem = [&](uint32_t kk0, uint32_t kk1, int idx)->uint32_t{
    uint32_t o0,o1;
    if (idx < T_STEPS){ tf2x32(kk0,kk1,(uint32_t)idx,(uint32_t)(T_STEPS+idx),o0,o1); return o0; }
    int i = idx - T_STEPS;
    tf2x32(kk0,kk1,(uint32_t)i,(uint32_t)(T_STEPS+i),o0,o1); return o1;
  };
  uint32_t n0 = splitElem(kA0,kA1, 2*t);
  uint32_t n1 = splitElem(kA0,kA1, 2*t+1);
  uint32_t r0 = splitElem(kB0,kB1, 2*t);
  uint32_t r1 = splitElem(kB0,kB1, 2*t+1);
  knKeys[2*t] = n0; knKeys[2*t+1] = n1;
  uint32_t o0,o1; tf2x32(r0,r1,0u,0u,o0,o1);
  u0Tab[t] = __uint_as_float((o0>>9) | 0x3f800000u) - 1.0f;
}

// ---------------- kernel 2: noise table ----------------
__global__ void k_noise(const uint32_t* __restrict__ knKeys, float* __restrict__ noiseTab){
  int t = blockIdx.x;
  uint32_t k0 = knKeys[2*t], k1 = knKeys[2*t+1];
  const int half = N_PART/2;
  const float lo = -0.99999994f;
  for (int i = threadIdx.x; i < half; i += blockDim.x){
    uint32_t o0,o1; tf2x32(k0,k1,(uint32_t)i,(uint32_t)(half+i),o0,o1);
    float ua = __uint_as_float((o0>>9)|0x3f800000u) - 1.0f;
    float ub = __uint_as_float((o1>>9)|0x3f800000u) - 1.0f;
    float va = fmaxf(lo, ua*2.0f + lo);
    float vb = fmaxf(lo, ub*2.0f + lo);
    float na = 1.4142135623730951f * erfinv_xla(va);
    float nb = 1.4142135623730951f * erfinv_xla(vb);
    noiseTab[(size_t)t*N_PART + i]        = 0.005f * na;
    noiseTab[(size_t)t*N_PART + half + i] = 0.005f * nb;
  }
}

// ---------------- kernel 3: (u, sI)-grid MLP GEMM ----------------
__global__ __launch_bounds__(256) void k_gemm(
    const float* __restrict__ W1, const float* __restrict__ b1,
    const float* __restrict__ W2, const float* __restrict__ b2,
    const float* __restrict__ W3, float* __restrict__ Zpart)
{
  __shared__ float sA[32][64];
  __shared__ float sB[32][129];
  __shared__ float sSoc[64], sSI[64];
  __shared__ float sRed[64][17];

  const int tid = threadIdx.x;
  const int m0 = blockIdx.x * 64;
  const int n0 = blockIdx.y * 128;

  if (tid < 64){
    int r = m0 + tid; if (r >= M2TOT) r = M2TOT-1;
    int k = r / SIKNOTS;
    int j = r - k*SIKNOTS;
    float u = (float)k * (1.0f/128.0f);
    sSoc[tid] = u*u;
    sSI[tid]  = SI_LO + SI_H * (float)j;
  }
  __syncthreads();

  const int tx = tid & 15;
  const int ty = tid >> 4;
  float acc[4][8];
  #pragma unroll
  for (int i=0;i<4;i++)
    #pragma unroll
    for (int q=0;q<8;q++) acc[i][q] = 0.0f;

  for (int kc = 0; kc < 1024; kc += 32){
    {
      int base = tid*8;
      int jj = base >> 6;
      int mm = base & 63;
      int j = kc + jj;
      float w0 = W1[2*j], w1v = W1[2*j+1], bb = b1[j];
      #pragma unroll
      for (int e=0;e<8;e++){
        int m = mm + e;
        float pre = sSoc[m]*w0 + sSI[m]*w1v + bb;
        sA[jj][m] = 1.0f/(1.0f + expf(-pre));
      }
    }
    {
      int nl = tid & 127;
      int h  = tid >> 7;
      const float* src = W2 + (size_t)(n0 + nl)*1024 + kc + h*16;
      float4 v0 = *(const float4*)(src+0);
      float4 v1 = *(const float4*)(src+4);
      float4 v2 = *(const float4*)(src+8);
      float4 v3 = *(const float4*)(src+12);
      int kb = h*16;
      sB[kb+ 0][nl]=v0.x; sB[kb+ 1][nl]=v0.y; sB[kb+ 2][nl]=v0.z; sB[kb+ 3][nl]=v0.w;
      sB[kb+ 4][nl]=v1.x; sB[kb+ 5][nl]=v1.y; sB[kb+ 6][nl]=v1.z; sB[kb+ 7][nl]=v1.w;
      sB[kb+ 8][nl]=v2.x; sB[kb+ 9][nl]=v2.y; sB[kb+10][nl]=v2.z; sB[kb+11][nl]=v2.w;
      sB[kb+12][nl]=v3.x; sB[kb+13][nl]=v3.y; sB[kb+14][nl]=v3.z; sB[kb+15][nl]=v3.w;
    }
    __syncthreads();
    #pragma unroll
    for (int kk=0;kk<32;kk++){
      float a_[4], b_[8];
      #pragma unroll
      for (int i=0;i<4;i++) a_[i] = sA[kk][ty*4+i];
      #pragma unroll
      for (int q=0;q<8;q++) b_[q] = sB[kk][tx*8+q];
      #pragma unroll
      for (int i=0;i<4;i++)
        #pragma unroll
        for (int q=0;q<8;q++) acc[i][q] = fmaf(a_[i], b_[q], acc[i][q]);
    }
    __syncthreads();
  }
  float part[4] = {0.f,0.f,0.f,0.f};
  #pragma unroll
  for (int q=0;q<8;q++){
    int n = n0 + tx*8 + q;
    float bb = b2[n], w3 = W3[n];
    #pragma unroll
    for (int i=0;i<4;i++){
      float h = 1.0f/(1.0f + expf(-(acc[i][q] + bb)));
      part[i] = fmaf(w3, h, part[i]);
    }
  }
  #pragma unroll
  for (int i=0;i<4;i++) sRed[ty*4+i][tx] = part[i];
  __syncthreads();
  if (tid < 64){
    int r = m0 + tid;
    if (r < M2TOT){
      float s = 0.0f;
      #pragma unroll
      for (int x=0;x<16;x++) s += sRed[tid][x];
      Zpart[(size_t)blockIdx.y*M2TOT + r] = s;
    }
  }
}

// ---------------- kernel 4a: combine Z parts ----------------
__global__ void k_tabZ(const float* __restrict__ Zpart, const float* __restrict__ b3,
                       float* __restrict__ Z2D){
  int r = blockIdx.x*blockDim.x + threadIdx.x;
  if (r >= M2TOT) return;
  Z2D[r] = ((Zpart[r] + Zpart[M2TOT+r]) + Zpart[2*M2TOT+r]) + Zpart[3*M2TOT+r] + b3[0];
}

// ---------------- kernel 4b: per-(t,k) sI-interp + voc -> coarse G table ----------------
__global__ void k_tabG(const float* __restrict__ Z2D, const float* __restrict__ current,
                       float* __restrict__ Gtab){
  int m = blockIdx.x*blockDim.x + threadIdx.x;
  if (m >= T_STEPS*UKNOTS) return;
  int t = m / UKNOTS;
  int k = m - t*UKNOTS;
  float It = current[t];
  float sI = (It + 2.0f) * 0.25f;
  float x = (sI - SI_LO) * (1.0f/SI_H);
  int c = (int)x; if (c < 1) c = 1; if (c > 65) c = 65;
  float xi = x - (float)c;
  const float* zp = Z2D + k*SIKNOTS + (c-1);
  float y0 = zp[0], y1 = zp[1], y2 = zp[2], y3 = zp[3];
  float xm1 = xi - 1.0f, xm2 = xi - 2.0f, xp1 = xi + 1.0f;
  float w0 = -(1.0f/6.0f) * xi  * xm1 * xm2;
  float w1 =  0.5f        * xp1 * xm1 * xm2;
  float w2 = -0.5f        * xi  * xp1 * xm2;
  float w3 =  (1.0f/6.0f) * xi  * xp1 * xm1;
  float z = ((w0*y0 + w1*y1) + w2*y2) + w3*y3;
  double u = (double)k / 128.0;
  double s = u*u;
  const double vL=-1.59614486, v0=4.13646328, gam=0.63726463, alp=1.40174122, bet=2.54478965;
  double voc = vL + (v0-vL)*exp(gam*(s-1.0)) + alp*vL*(s-1.0)
             + (1.0-alp)*vL*(exp(-bet) - exp(-bet*sqrt(s)));
  Gtab[m] = (float)voc - It*z;
}

// ---------------- kernel 4c: coarse cubic -> fine scalar table ----------------
__device__ __forceinline__ float cubicEval(const float* __restrict__ g, int cf){
  float x = (float)cf * (1.0f/16.0f);
  int cc = (int)x; if (cc > 127) cc = 127;
  float xi = x - (float)cc;
  float y0 = (cc == 0) ? g[1] : g[cc-1];   // even mirror in u
  float y1 = g[cc], y2 = g[cc+1], y3 = g[cc+2];
  float xm1 = xi - 1.0f, xm2 = xi - 2.0f, xp1 = xi + 1.0f;
  float w0 = -(1.0f/6.0f) * xi  * xm1 * xm2;
  float w1 =  0.5f        * xp1 * xm1 * xm2;
  float w2 = -0.5f        * xi  * xp1 * xm2;
  float w3 =  (1.0f/6.0f) * xi  * xp1 * xm1;
  return ((w0*y0 + w1*y1) + w2*y2) + w3*y3;
}
__global__ void k_tabFine(const float* __restrict__ Gtab, float* __restrict__ TabF){
  int m = blockIdx.x*blockDim.x + threadIdx.x;
  if (m >= T_STEPS*FKN) return;
  int t = m / FKN;
  int c = m - t*FKN;
  TabF[m] = cubicEval(Gtab + t*UKNOTS, c);
}

// linear interp on scalar fine table (LDS)
__device__ __forceinline__ float interpS(const float* __restrict__ tab, float s){
  float x = sqrtf(s) * 2048.0f;
  float cf = floorf(x);
  cf = fminf(cf, 2047.0f);
  int c = (int)cf;
  float xi = x - cf;
  float y0 = tab[c], y1 = tab[c+1];
  return fmaf(xi, y1 - y0, y0);
}

// ---------------- kernel 5: sequential particle filter (single block, 1024 thr) ----------------
// Isolated changes this round (kernel is LDS-unit-throughput-bound; remove DS ops):
//  1. Combine section: 13 serial ds_bpermute (dG xor-reduce, pf scan, Sv, pfEx,
//     3 wave-broadcasts) -> DPP (VALU) + readlane. Bitwise-exact:
//     - min-reduce reassociated (min fully associative; same minimum element)
//     - sum-scan via row_shr + bound_ctrl-0-fill: valid-lane operands identical
//       to __shfl_up Kogge-Stone; invalid lanes add +0.0 to positive values
//     - readlane replaces __shfl for wave-uniform indices
//     All 64 lanes compute rows redundantly on ddW[lane&15] (no divergent branch).
//  2. idxL back to a SINGLE buffer (R2 scheme): the R3 dbuf of idxL bought nothing.
//     read(t) completes before B1(t+1) (BAR_LGKM drains lgkm before barrier);
//     scatter(t+1) writes after B1(t+1) -> no WAR race. Stale tags (t-1) lose
//     the max-scan to current tags (t<<13 monotone). socP stays dbuf'd (no B3).
// LDS: 64K socP + 16.4K tabF + 32K idxL + 128 B = 112.5 KiB.
__global__ __launch_bounds__(1024) void k_filter(
    const float* __restrict__ soc_init, const float* __restrict__ current,
    const float* __restrict__ vmeas,   const float* __restrict__ Ecrit,
    const float* __restrict__ TabF,    const float* __restrict__ noiseTab,
    const float* __restrict__ u0Tab,
    float* __restrict__ vHist, float* __restrict__ sHist,
    long strideT, long strideP, float* __restrict__ lossOut)
{
  __shared__ __align__(16) float socP[2][N_PART];  // 64 KiB dbuf (exact f32 state)
  __shared__ __align__(16) float tabF[2][2052];    // 16.4 KiB dbuf
  __shared__ __align__(16) int   idxL[N_PART];     // 32 KiB resample tags (single buf)
  __shared__ float ddW[16];
  __shared__ float sWv[16];

  const int tid = threadIdx.x;
  const int lane = tid & 63;
  const int wv = tid >> 6;
  const float ec = Ecrit[0];

  // prologue
  tabF[0][tid]      = TabF[tid];
  tabF[0][1024+tid] = TabF[1024+tid];
  if (tid == 0) tabF[0][2048] = TabF[2048];
  {
    int4 neg = {-1,-1,-1,-1};
    int4* ip = (int4*)&idxL[tid*8];
    ip[0] = neg; ip[1] = neg;
  }
  const float4* nzp = (const float4*)noiseTab + tid*2;
  float4 nzA = nzp[0], nzB = nzp[1];
  float soc[8], V[8];
  __syncthreads();
  #pragma unroll
  for (int k=0;k<8;k++){
    float s = soc_init[tid*8+k];
    soc[k] = s;
    V[k] = interpS(tabF[0], s);
  }
  float loss = 0.0f;
  float Iprev = current[0];

  for (int t=0; t<T_STEPS; t++){
    const int cur = t & 1, nxt = cur ^ 1;
    const int tagBase = t << 13;
    float* __restrict__ sp = socP[cur];
    int*   __restrict__ il = idxL;

    // prefetch next-step table + noise into registers
    int tn = (t+1 < T_STEPS) ? t+1 : t;
    const float* tRow = TabF + (size_t)tn * FKN;
    float pf0 = tRow[tid];
    float pf1 = tRow[1024+tid];
    float pf2 = 0.0f;
    if (tid == 0) pf2 = tRow[2048];
    const float4* nzn = (const float4*)(noiseTab + (size_t)tn*N_PART) + tid*2;
    float4 nzA2 = nzn[0], nzB2 = nzn[1];

    float It = current[t];
    float vm = vmeas[t];
    float u0 = u0Tab[t];
    float coef = -(Iprev / 26267.160775850585f) * ec;
    float nz[8] = {nzA.x,nzA.y,nzA.z,nzA.w,nzB.x,nzB.y,nzB.z,nzB.w};
    const float* tf = tabF[cur];

    // ---- phase 1: propagate (vectorized socP store), then measure ----
    float s8[8];
    #pragma unroll
    for (int k=0;k<8;k++){
      float s = fmaf(V[k], coef, soc[k]);
      s = s + nz[k];
      s = fminf(1.0f, fmaxf(s, 1e-10f));
      s8[k] = s;
    }
    {
      float4 a = {s8[0],s8[1],s8[2],s8[3]}, b = {s8[4],s8[5],s8[6],s8[7]};
      float4* dst = (float4*)&sp[tid*8];
      dst[0] = a; dst[1] = b;
    }
    float dd[8];
    #pragma unroll
    for (int k=0;k<8;k++){
      float Vn = interpS(tf, s8[k]);
      V[k] = Vn;
      float d = Vn - vm;
      dd[k] = d*d;
    }
    if (strideP == 1){
      float4 a = {V[0],V[1],V[2],V[3]}, b = {V[4],V[5],V[6],V[7]};
      float4* dst = (float4*)(vHist + (size_t)t*strideT + tid*8);
      dst[0] = a; dst[1] = b;
    } else {
      #pragma unroll
      for (int k=0;k<8;k++) vHist[(size_t)t*strideT + (size_t)(tid*8+k)*strideP] = V[k];
    }

    // per-thread min fold (tree, exact) then 64-lane min via DPP (exact)
    float m01 = fminf(dd[0],dd[1]), m23 = fminf(dd[2],dd[3]);
    float m45 = fminf(dd[4],dd[5]), m67 = fminf(dd[6],dd[7]);
    float dmin = fminf(fminf(m01,m23), fminf(m45,m67));
    dmin = dppMinAll64(dmin);

    // exp prefix (wave frame; order-preserving)
    float ebase = DD2E * dmin;
    float run = 0.0f, cp[8];
    #pragma unroll
    for (int k=0;k<8;k++){
      float e = exp2f(fmaf(dd[k], -DD2E, ebase));
      run += e;
      cp[k] = run;
    }
    float sc = run;
    #pragma unroll
    for (int off=1; off<64; off<<=1){
      float o = __shfl_up(sc, (unsigned)off);
      if (lane >= off) sc += o;
    }
    float excl = __shfl_up(sc, 1);       // bitwise == prev lane's inclusive sc
    if (lane == 0) excl = 0.0f;
    if (lane == 63){ ddW[wv] = dmin; sWv[wv] = sc; }
    BAR_LGKM();                          // B1 (LDS-only ordering; vHist store overlaps)

    // commit prefetched table into the other buffer (drains during combine; read after B2(t)->phase1(t+1))
    tabF[nxt][tid]      = pf0;
    tabF[nxt][1024+tid] = pf1;
    if (tid == 0) tabF[nxt][2048] = pf2;

    // ---- combine wave stats: DPP within-16, all lanes redundant (bitwise-exact) ----
    float b0, bI, scl;
    {
      float dv = ddW[lane & 15];         // 4-lane same-addr broadcast, conflict-free
      float sw = sWv[lane & 15];
      float dG = dv;
      dG = fminf(dG, dppf<0xB1,0xf>(dG));    // quad_perm [1,0,3,2]  (xor 1)
      dG = fminf(dG, dppf<0x4E,0xf>(dG));    // quad_perm [2,3,0,1]  (xor 2)
      dG = fminf(dG, dppf<0x124,0xf>(dG));   // row_ror:4
      dG = fminf(dG, dppf<0x128,0xf>(dG));   // row_ror:8  -> 16-lane min everywhere
      float ew = exp2f(-DD2E * (dv - dG));
      float pfv = sw * ew;
      pfv += dppzf<0x111>(pfv);              // row_shr:1 (+0 fill) — bitwise == shfl_up KS
      pfv += dppzf<0x112>(pfv);              // row_shr:2
      pfv += dppzf<0x114>(pfv);              // row_shr:4
      pfv += dppzf<0x118>(pfv);              // row_shr:8
      float Sv = rdlanef(pfv, 15);
      float invS = 1.0f / Sv;
      float pfEx = dppzf<0x111>(pfv);        // lane0 -> 0 (== lane==0 fixup)
      int swv = __builtin_amdgcn_readfirstlane(wv);
      b0  = rdlanef(pfEx * invS, swv);       // exclusive block prefix, normalized
      bI  = rdlanef(pfv  * invS, swv);       // inclusive; bitwise == next wave's b0
      scl = rdlanef(ew   * invS, swv);
      if (tid == 0)
        loss = ((loss + (LOGNU - DD2LW*dG)) + logf(Sv)) - LOG8192;
    }

    // ---- slot inversion + tagged LDS scatter (bitwise-exact seams, owners only) ----
    float scl8 = scl * 8192.0f;
    float b8   = fmaf(b0, 8192.0f, -u0);       // wave base in slot units
    float bth  = fmaf(excl, scl8, b8);
    int aP0 = __float2int_rd(bth);
    if (aP0 < -1) aP0 = -1;
    int raw[8];
    #pragma unroll
    for (int k=0;k<7;k++){
      int a = __float2int_rd(fmaf(cp[k], scl8, bth));
      raw[k] = (a > N_PART-1) ? N_PART-1 : a;
    }
    {
      int a;
      if (tid*8+7 == N_PART-1){
        a = N_PART-1;
      } else {
        if (lane == 63) a = __float2int_rd(fmaf(bI, 8192.0f, -u0));  // == next wave's base
        else            a = __float2int_rd(fmaf(sc, scl8, b8));      // == next thread's base
        if (a > N_PART-1) a = N_PART-1;
      }
      raw[7] = a;
    }
    // prefix-max over raw (Kogge-Stone depth 3, exact == serial max chain)
    int c1[8], c2[8], c4[8];
    c1[0]=raw[0];
    #pragma unroll
    for (int k=1;k<8;k++) c1[k] = max(raw[k], raw[k-1]);
    c2[0]=c1[0]; c2[1]=c1[1];
    #pragma unroll
    for (int k=2;k<8;k++) c2[k] = max(c1[k], c1[k-2]);
    #pragma unroll
    for (int k=0;k<4;k++) c4[k] = c2[k];
    #pragma unroll
    for (int k=4;k<8;k++) c4[k] = max(c2[k], c2[k-4]);
    #pragma unroll
    for (int k=0;k<8;k++){
      int aprev = (k==0) ? aP0 : max(aP0, c4[k-1]);
      int a     = max(aP0, c4[k]);
      int st = aprev + 1;
      if (a >= st){                              // owners only
        int tag = tagBase + tid*8 + k;
        atomicMax(&il[st], tag);                 // ds_max (LDS)
        for (int r = (st>>9)+1; (r<<9) <= a; ++r)
          atomicMax(&il[r<<9], tag);             // 512-region anchors
      }
    }
    BAR_LGKM();                          // B2 (LDS-only: ds atomics + socP ordering)

    // ---- slot phase: b128 idx reads, register prefix-max, DPP wave max-scan, gather ----
    int4 q0 = *(const int4*)&il[tid*8+0];
    int4 q1 = *(const int4*)&il[tid*8+4];
    int sl[8] = { q0.x, q0.y, q0.z, q0.w, q1.x, q1.y, q1.z, q1.w };
    int d1[8], d2[8], d4[8];
    d1[0]=sl[0];
    #pragma unroll
    for (int k=1;k<8;k++) d1[k] = max(sl[k], sl[k-1]);
    d2[0]=d1[0]; d2[1]=d1[1];
    #pragma unroll
    for (int k=2;k<8;k++) d2[k] = max(d1[k], d1[k-2]);
    #pragma unroll
    for (int k=0;k<4;k++) d4[k] = d2[k];
    #pragma unroll
    for (int k=4;k<8;k++) d4[k] = max(d2[k], d2[k-4]);   // d4[k] = prefix-max sl[0..k]
    int scn = dppMaxScan64(d4[7]);       // inclusive across 64 lanes (exact)
    int ex = __shfl_up(scn, 1);
    if (lane == 0) ex = -1;              // wave-chunk start covered by 512-anchor
    float sn[8];
    #pragma unroll
    for (int k=0;k<8;k++){
      int run2 = max(ex, d4[k]);
      int idx = run2 - tagBase;
      if (idx < 0 || idx > N_PART-1) idx = tid*8+k;   // safety net (should not trigger)
      sn[k] = sp[idx];
    }
    if (strideP == 1){
      float4 a = {sn[0],sn[1],sn[2],sn[3]}, b = {sn[4],sn[5],sn[6],sn[7]};
      float4* dst = (float4*)(sHist + (size_t)t*strideT + tid*8);
      dst[0] = a; dst[1] = b;
    } else {
      #pragma unroll
      for (int k=0;k<8;k++) sHist[(size_t)t*strideT + (size_t)(tid*8+k)*strideP] = sn[k];
    }
    #pragma unroll
    for (int k=0;k<8;k++) soc[k] = sn[k];
    Iprev = It;
    nzA = nzA2; nzB = nzB2;
    // no B3: next step writes socP[nxt]; idxL read(t) completes before B1(t+1)
    // (BAR_LGKM drains lgkm), scatter(t+1) writes after B1(t+1) -> no WAR race.
  }
  if (tid == 0) lossOut[0] = loss;
}

// ---------------- kernel 6: (T,N) -> (N,T) transpose ----------------
__global__ void k_transpose(const float* __restrict__ vS, const float* __restrict__ sS,
                            float* __restrict__ outV, float* __restrict__ outS){
  __shared__ float tile[32][33];
  const float* src = blockIdx.z ? sS : vS;
  float* dst = blockIdx.z ? outS : outV;
  int t0 = blockIdx.x*32, n0 = blockIdx.y*32;
  int tx = threadIdx.x, ty = threadIdx.y;
  #pragma unroll
  for (int r=0;r<4;r++)
    tile[ty+8*r][tx] = src[(size_t)(t0+ty+8*r)*N_PART + n0 + tx];
  __syncthreads();
  #pragma unroll
  for (int r=0;r<4;r++)
    dst[(size_t)(n0+ty+8*r)*T_STEPS + t0 + tx] = tile[tx][ty+8*r];
}

extern "C" void kernel_launch(void* const* d_in, const int* in_sizes, int n_in,
                              void* d_out, int out_size, void* d_ws, size_t ws_size,
                              hipStream_t stream){
  const float* soc_init = (const float*)d_in[0];
  const float* current  = (const float*)d_in[1];
  const float* vmeas    = (const float*)d_in[2];
  const float* W1 = (const float*)d_in[3];
  const float* b1 = (const float*)d_in[4];
  const float* W2 = (const float*)d_in[5];
  const float* b2 = (const float*)d_in[6];
  const float* W3 = (const float*)d_in[7];
  const float* b3 = (const float*)d_in[8];
  const float* Ec = (const float*)d_in[9];

  float* outLoss = (float*)d_out;
  float* outV = outLoss + 1;
  float* outS = outV + (size_t)N_PART*T_STEPS;

  char* p = (char*)d_ws;
  auto carve = [&](size_t bytes)->char*{ char* r = p; p += (bytes + 255) & ~(size_t)255; return r; };
  uint32_t* knKeys  = (uint32_t*)carve((size_t)2*T_STEPS*4);
  float* u0Tab      = (float*)carve((size_t)T_STEPS*4);
  float* Zpart      = (float*)carve((size_t)4*M2TOT*4);
  float* Z2D        = (float*)carve((size_t)M2TOT*4);
  float* Gtab       = (float*)carve((size_t)T_STEPS*UKNOTS*4);
  float* TabF       = (float*)carve((size_t)T_STEPS*FKN*4);
  float* noiseTab   = (float*)carve((size_t)N_PART*T_STEPS*4);
  float* vS         = (float*)carve((size_t)N_PART*T_STEPS*4);
  float* sS         = (float*)carve((size_t)N_PART*T_STEPS*4);
  bool useScratch   = ((size_t)(p - (char*)d_ws) <= ws_size);

  k_keys<<<dim3((T_STEPS+255)/256), dim3(256), 0, stream>>>(knKeys, u0Tab);
  k_noise<<<dim3(T_STEPS), dim3(256), 0, stream>>>(knKeys, noiseTab);
  k_gemm<<<dim3((M2TOT+63)/64, 4), dim3(256), 0, stream>>>(W1, b1, W2, b2, W3, Zpart);
  k_tabZ<<<dim3((M2TOT+255)/256), dim3(256), 0, stream>>>(Zpart, b3, Z2D);
  k_tabG<<<dim3((T_STEPS*UKNOTS+255)/256), dim3(256), 0, stream>>>(Z2D, current, Gtab);
  k_tabFine<<<dim3((T_STEPS*FKN+255)/256), dim3(256), 0, stream>>>(Gtab, TabF);

  if (useScratch){
    k_filter<<<dim3(1), dim3(1024), 0, stream>>>(soc_init, current, vmeas, Ec, TabF, noiseTab,
                                                 u0Tab, vS, sS, (long)N_PART, 1L, outLoss);
    k_transpose<<<dim3(T_STEPS/32, N_PART/32, 2), dim3(32,8), 0, stream>>>(vS, sS, outV, outS);
  } else {
    k_filter<<<dim3(1), dim3(1024), 0, stream>>>(soc_init, current, vmeas, Ec, TabF, noiseTab,
                                                 u0Tab, outV, outS, 1L, (long)T_STEPS, outLoss);
  }
}

// Round 6
// 4959.779 us; speedup vs baseline: 1.3525x; 1.0199x over previous
//
#include <hip/hip_runtime.h>
#include <stdint.h>
#include <math.h>

#define N_PART 8192
#define T_STEPS 1024
#define UKNOTS 130            // coarse u-knots k=0..129, u=k/128 (cubic source grid)
#define SIKNOTS 68            // sI-knots j=0..67, sI = SI_LO + j*SI_H
#define M2TOT (UKNOTS*SIKNOTS)
#define FKN 2049              // fine linear grid in u: entries c=0..2048, u=c/2048
#define SI_LO 0.49375f
#define SI_H  0.00625f
#define LOGNU 3.6862316527834183f
#define LOG8192 9.010913347279288f
#define DD2LW 5000.0f                 // lw = LOGNU - 5000*dd, dd=(V-vm)^2
#define DD2E  7213.4752044448170f     // 5000*log2(e)

// LDS-only barrier: orders ds ops without draining outstanding global stores.
#define BAR_LGKM() asm volatile("s_waitcnt lgkmcnt(0)\n\ts_barrier" ::: "memory")

// ---- DPP helpers ----
// old=x, bound_ctrl=false: invalid lanes keep x -> identity for min/max.
template<int CTRL, int RM>
__device__ __forceinline__ int dppi(int x){
  return __builtin_amdgcn_update_dpp(x, x, CTRL, RM, 0xf, false);
}
template<int CTRL, int RM>
__device__ __forceinline__ float dppf(float x){
  return __int_as_float(__builtin_amdgcn_update_dpp(__float_as_int(x), __float_as_int(x), CTRL, RM, 0xf, false));
}
// bound_ctrl=true: invalid lanes produce 0.0f -> "+0" identity for the float scan
// (operands for valid lanes are bitwise-identical to __shfl_up Kogge-Stone).
template<int CTRL>
__device__ __forceinline__ float dppzf(float x){
  return __int_as_float(__builtin_amdgcn_update_dpp(0, __float_as_int(x), CTRL, 0xf, 0xf, true));
}
__device__ __forceinline__ float rdlanef(float x, int l){
  return __int_as_float(__builtin_amdgcn_readlane(__float_as_int(x), l));
}
// 64-lane inclusive max-scan: row_shr 1/2/4/8 then row_bcast15 (rows1,3) + row_bcast31 (rows2,3)
__device__ __forceinline__ int dppMaxScan64(int x){
  x = max(x, dppi<0x111,0xf>(x));
  x = max(x, dppi<0x112,0xf>(x));
  x = max(x, dppi<0x114,0xf>(x));
  x = max(x, dppi<0x118,0xf>(x));
  x = max(x, dppi<0x142,0xa>(x));
  x = max(x, dppi<0x143,0xc>(x));
  return x;
}
// 64-lane min-reduce (exact): prefix-min scan, total lands in lane 63, broadcast via readlane
__device__ __forceinline__ float dppMinAll64(float x){
  x = fminf(x, dppf<0x111,0xf>(x));
  x = fminf(x, dppf<0x112,0xf>(x));
  x = fminf(x, dppf<0x114,0xf>(x));
  x = fminf(x, dppf<0x118,0xf>(x));
  x = fminf(x, dppf<0x142,0xa>(x));
  x = fminf(x, dppf<0x143,0xc>(x));
  return __int_as_float(__builtin_amdgcn_readlane(__float_as_int(x), 63));
}

// ---------------- Threefry-2x32 (exact JAX semantics) ----------------
__device__ __forceinline__ uint32_t rotl32(uint32_t x, int d){ return (x<<d)|(x>>(32-d)); }

__device__ __forceinline__ void tf2x32(uint32_t k0, uint32_t k1, uint32_t c0, uint32_t c1,
                                       uint32_t& o0, uint32_t& o1){
  uint32_t ks2 = k0 ^ k1 ^ 0x1BD11BDAu;
  uint32_t x0 = c0 + k0, x1 = c1 + k1;
  #define TFR(r) { x0 += x1; x1 = rotl32(x1, r); x1 ^= x0; }
  TFR(13) TFR(15) TFR(26) TFR(6)
  x0 += k1;  x1 += ks2 + 1u;
  TFR(17) TFR(29) TFR(16) TFR(24)
  x0 += ks2; x1 += k0 + 2u;
  TFR(13) TFR(15) TFR(26) TFR(6)
  x0 += k0;  x1 += k1 + 3u;
  TFR(17) TFR(29) TFR(16) TFR(24)
  x0 += k1;  x1 += ks2 + 4u;
  TFR(13) TFR(15) TFR(26) TFR(6)
  x0 += ks2; x1 += k0 + 5u;
  #undef TFR
  o0 = x0; o1 = x1;
}

__device__ __forceinline__ float erfinv_xla(float x){
  float w = -log1pf(-x*x);
  float p;
  if (w < 5.0f){
    w -= 2.5f;
    p = 2.81022636e-08f;
    p = fmaf(p, w, 3.43273939e-07f);
    p = fmaf(p, w, -3.5233877e-06f);
    p = fmaf(p, w, -4.39150654e-06f);
    p = fmaf(p, w, 0.00021858087f);
    p = fmaf(p, w, -0.00125372503f);
    p = fmaf(p, w, -0.00417768164f);
    p = fmaf(p, w, 0.246640727f);
    p = fmaf(p, w, 1.50140941f);
  } else {
    w = sqrtf(w) - 3.0f;
    p = -0.000200214257f;
    p = fmaf(p, w, 0.000100950558f);
    p = fmaf(p, w, 0.00134934322f);
    p = fmaf(p, w, -0.00367342844f);
    p = fmaf(p, w, 0.00573950773f);
    p = fmaf(p, w, -0.0076224613f);
    p = fmaf(p, w, 0.00943887047f);
    p = fmaf(p, w, 1.00167406f);
    p = fmaf(p, w, 2.83297682f);
  }
  return p * x;
}

// ---------------- kernel 1: per-step keys + u0 ----------------
__global__ void k_keys(uint32_t* __restrict__ knKeys, float* __restrict__ u0Tab){
  int t = blockIdx.x*blockDim.x + threadIdx.x;
  if (t >= T_STEPS) return;
  uint32_t kA0,kA1,kB0,kB1;
  tf2x32(0u,42u, 0u,0u, kA0,kA1);
  tf2x32(0u,42u, 0u,1u, kB0,kB1);
  auto splitElem = [&](uint32_t kk0, uint32_t kk1, int idx)->uint32_t{
    uint32_t o0,o1;
    if (idx < T_STEPS){ tf2x32(kk0,kk1,(uint32_t)idx,(uint32_t)(T_STEPS+idx),o0,o1); return o0; }
    int i = idx - T_STEPS;
    tf2x32(kk0,kk1,(uint32_t)i,(uint32_t)(T_STEPS+i),o0,o1); return o1;
  };
  uint32_t n0 = splitElem(kA0,kA1, 2*t);
  uint32_t n1 = splitElem(kA0,kA1, 2*t+1);
  uint32_t r0 = splitElem(kB0,kB1, 2*t);
  uint32_t r1 = splitElem(kB0,kB1, 2*t+1);
  knKeys[2*t] = n0; knKeys[2*t+1] = n1;
  uint32_t o0,o1; tf2x32(r0,r1,0u,0u,o0,o1);
  u0Tab[t] = __uint_as_float((o0>>9) | 0x3f800000u) - 1.0f;
}

// ---------------- kernel 2: noise table ----------------
__global__ void k_noise(const uint32_t* __restrict__ knKeys, float* __restrict__ noiseTab){
  int t = blockIdx.x;
  uint32_t k0 = knKeys[2*t], k1 = knKeys[2*t+1];
  const int half = N_PART/2;
  const float lo = -0.99999994f;
  for (int i = threadIdx.x; i < half; i += blockDim.x){
    uint32_t o0,o1; tf2x32(k0,k1,(uint32_t)i,(uint32_t)(half+i),o0,o1);
    float ua = __uint_as_float((o0>>9)|0x3f800000u) - 1.0f;
    float ub = __uint_as_float((o1>>9)|0x3f800000u) - 1.0f;
    float va = fmaxf(lo, ua*2.0f + lo);
    float vb = fmaxf(lo, ub*2.0f + lo);
    float na = 1.4142135623730951f * erfinv_xla(va);
    float nb = 1.4142135623730951f * erfinv_xla(vb);
    noiseTab[(size_t)t*N_PART + i]        = 0.005f * na;
    noiseTab[(size_t)t*N_PART + half + i] = 0.005f * nb;
  }
}

// ---------------- kernel 3: (u, sI)-grid MLP GEMM ----------------
__global__ __launch_bounds__(256) void k_gemm(
    const float* __restrict__ W1, const float* __restrict__ b1,
    const float* __restrict__ W2, const float* __restrict__ b2,
    const float* __restrict__ W3, float* __restrict__ Zpart)
{
  __shared__ float sA[32][64];
  __shared__ float sB[32][129];
  __shared__ float sSoc[64], sSI[64];
  __shared__ float sRed[64][17];

  const int tid = threadIdx.x;
  const int m0 = blockIdx.x * 64;
  const int n0 = blockIdx.y * 128;

  if (tid < 64){
    int r = m0 + tid; if (r >= M2TOT) r = M2TOT-1;
    int k = r / SIKNOTS;
    int j = r - k*SIKNOTS;
    float u = (float)k * (1.0f/128.0f);
    sSoc[tid] = u*u;
    sSI[tid]  = SI_LO + SI_H * (float)j;
  }
  __syncthreads();

  const int tx = tid & 15;
  const int ty = tid >> 4;
  float acc[4][8];
  #pragma unroll
  for (int i=0;i<4;i++)
    #pragma unroll
    for (int q=0;q<8;q++) acc[i][q] = 0.0f;

  for (int kc = 0; kc < 1024; kc += 32){
    {
      int base = tid*8;
      int jj = base >> 6;
      int mm = base & 63;
      int j = kc + jj;
      float w0 = W1[2*j], w1v = W1[2*j+1], bb = b1[j];
      #pragma unroll
      for (int e=0;e<8;e++){
        int m = mm + e;
        float pre = sSoc[m]*w0 + sSI[m]*w1v + bb;
        sA[jj][m] = 1.0f/(1.0f + expf(-pre));
      }
    }
    {
      int nl = tid & 127;
      int h  = tid >> 7;
      const float* src = W2 + (size_t)(n0 + nl)*1024 + kc + h*16;
      float4 v0 = *(const float4*)(src+0);
      float4 v1 = *(const float4*)(src+4);
      float4 v2 = *(const float4*)(src+8);
      float4 v3 = *(const float4*)(src+12);
      int kb = h*16;
      sB[kb+ 0][nl]=v0.x; sB[kb+ 1][nl]=v0.y; sB[kb+ 2][nl]=v0.z; sB[kb+ 3][nl]=v0.w;
      sB[kb+ 4][nl]=v1.x; sB[kb+ 5][nl]=v1.y; sB[kb+ 6][nl]=v1.z; sB[kb+ 7][nl]=v1.w;
      sB[kb+ 8][nl]=v2.x; sB[kb+ 9][nl]=v2.y; sB[kb+10][nl]=v2.z; sB[kb+11][nl]=v2.w;
      sB[kb+12][nl]=v3.x; sB[kb+13][nl]=v3.y; sB[kb+14][nl]=v3.z; sB[kb+15][nl]=v3.w;
    }
    __syncthreads();
    #pragma unroll
    for (int kk=0;kk<32;kk++){
      float a_[4], b_[8];
      #pragma unroll
      for (int i=0;i<4;i++) a_[i] = sA[kk][ty*4+i];
      #pragma unroll
      for (int q=0;q<8;q++) b_[q] = sB[kk][tx*8+q];
      #pragma unroll
      for (int i=0;i<4;i++)
        #pragma unroll
        for (int q=0;q<8;q++) acc[i][q] = fmaf(a_[i], b_[q], acc[i][q]);
    }
    __syncthreads();
  }
  float part[4] = {0.f,0.f,0.f,0.f};
  #pragma unroll
  for (int q=0;q<8;q++){
    int n = n0 + tx*8 + q;
    float bb = b2[n], w3 = W3[n];
    #pragma unroll
    for (int i=0;i<4;i++){
      float h = 1.0f/(1.0f + expf(-(acc[i][q] + bb)));
      part[i] = fmaf(w3, h, part[i]);
    }
  }
  #pragma unroll
  for (int i=0;i<4;i++) sRed[ty*4+i][tx] = part[i];
  __syncthreads();
  if (tid < 64){
    int r = m0 + tid;
    if (r < M2TOT){
      float s = 0.0f;
      #pragma unroll
      for (int x=0;x<16;x++) s += sRed[tid][x];
      Zpart[(size_t)blockIdx.y*M2TOT + r] = s;
    }
  }
}

// ---------------- kernel 4a: combine Z parts ----------------
__global__ void k_tabZ(const float* __restrict__ Zpart, const float* __restrict__ b3,
                       float* __restrict__ Z2D){
  int r = blockIdx.x*blockDim.x + threadIdx.x;
  if (r >= M2TOT) return;
  Z2D[r] = ((Zpart[r] + Zpart[M2TOT+r]) + Zpart[2*M2TOT+r]) + Zpart[3*M2TOT+r] + b3[0];
}

// ---------------- kernel 4b: per-(t,k) sI-interp + voc -> coarse G table ----------------
__global__ void k_tabG(const float* __restrict__ Z2D, const float* __restrict__ current,
                       float* __restrict__ Gtab){
  int m = blockIdx.x*blockDim.x + threadIdx.x;
  if (m >= T_STEPS*UKNOTS) return;
  int t = m / UKNOTS;
  int k = m - t*UKNOTS;
  float It = current[t];
  float sI = (It + 2.0f) * 0.25f;
  float x = (sI - SI_LO) * (1.0f/SI_H);
  int c = (int)x; if (c < 1) c = 1; if (c > 65) c = 65;
  float xi = x - (float)c;
  const float* zp = Z2D + k*SIKNOTS + (c-1);
  float y0 = zp[0], y1 = zp[1], y2 = zp[2], y3 = zp[3];
  float xm1 = xi - 1.0f, xm2 = xi - 2.0f, xp1 = xi + 1.0f;
  float w0 = -(1.0f/6.0f) * xi  * xm1 * xm2;
  float w1 =  0.5f        * xp1 * xm1 * xm2;
  float w2 = -0.5f        * xi  * xp1 * xm2;
  float w3 =  (1.0f/6.0f) * xi  * xp1 * xm1;
  float z = ((w0*y0 + w1*y1) + w2*y2) + w3*y3;
  double u = (double)k / 128.0;
  double s = u*u;
  const double vL=-1.59614486, v0=4.13646328, gam=0.63726463, alp=1.40174122, bet=2.54478965;
  double voc = vL + (v0-vL)*exp(gam*(s-1.0)) + alp*vL*(s-1.0)
             + (1.0-alp)*vL*(exp(-bet) - exp(-bet*sqrt(s)));
  Gtab[m] = (float)voc - It*z;
}

// ---------------- kernel 4c: coarse cubic -> fine scalar table ----------------
__device__ __forceinline__ float cubicEval(const float* __restrict__ g, int cf){
  float x = (float)cf * (1.0f/16.0f);
  int cc = (int)x; if (cc > 127) cc = 127;
  float xi = x - (float)cc;
  float y0 = (cc == 0) ? g[1] : g[cc-1];   // even mirror in u
  float y1 = g[cc], y2 = g[cc+1], y3 = g[cc+2];
  float xm1 = xi - 1.0f, xm2 = xi - 2.0f, xp1 = xi + 1.0f;
  float w0 = -(1.0f/6.0f) * xi  * xm1 * xm2;
  float w1 =  0.5f        * xp1 * xm1 * xm2;
  float w2 = -0.5f        * xi  * xp1 * xm2;
  float w3 =  (1.0f/6.0f) * xi  * xp1 * xm1;
  return ((w0*y0 + w1*y1) + w2*y2) + w3*y3;
}
__global__ void k_tabFine(const float* __restrict__ Gtab, float* __restrict__ TabF){
  int m = blockIdx.x*blockDim.x + threadIdx.x;
  if (m >= T_STEPS*FKN) return;
  int t = m / FKN;
  int c = m - t*FKN;
  TabF[m] = cubicEval(Gtab + t*UKNOTS, c);
}

// linear interp on scalar fine table (LDS)
__device__ __forceinline__ float interpS(const float* __restrict__ tab, float s){
  float x = sqrtf(s) * 2048.0f;
  float cf = floorf(x);
  cf = fminf(cf, 2047.0f);
  int c = (int)cf;
  float xi = x - cf;
  float y0 = tab[c], y1 = tab[c+1];
  return fmaf(xi, y1 - y0, y0);
}

// ---------------- kernel 5: sequential particle filter (single block, 1024 thr) ----------------
// Isolated changes this round (VALU-trim; ~90% single-CU VALUBusy -> cut issue count;
// all changes bitwise-exact):
//  1. propagate clamp via v_fmed3_f32 (1 op, identical select semantics for finite s).
//  2. scatter/slot prefix-max: Kogge-Stone (17 ops) -> serial chain (8 ops). Exact
//     (int max associative; identical values). 8-deep dep chain hidden by 4 waves/SIMD.
//  3. gather safety clamp -> single AND (mask 8191). Proven dead: every 512-block
//     base slot receives a current-step tag (partition property of owner spans +
//     region anchors), so run2-tagBase is always in [0,8191].
__global__ __launch_bounds__(1024) void k_filter(
    const float* __restrict__ soc_init, const float* __restrict__ current,
    const float* __restrict__ vmeas,   const float* __restrict__ Ecrit,
    const float* __restrict__ TabF,    const float* __restrict__ noiseTab,
    const float* __restrict__ u0Tab,
    float* __restrict__ vHist, float* __restrict__ sHist,
    long strideT, long strideP, float* __restrict__ lossOut)
{
  __shared__ __align__(16) float socP[2][N_PART];  // 64 KiB dbuf (exact f32 state)
  __shared__ __align__(16) float tabF[2][2052];    // 16.4 KiB dbuf
  __shared__ __align__(16) int   idxL[N_PART];     // 32 KiB resample tags (single buf)
  __shared__ float ddW[16];
  __shared__ float sWv[16];

  const int tid = threadIdx.x;
  const int lane = tid & 63;
  const int wv = tid >> 6;
  const float ec = Ecrit[0];

  // prologue
  tabF[0][tid]      = TabF[tid];
  tabF[0][1024+tid] = TabF[1024+tid];
  if (tid == 0) tabF[0][2048] = TabF[2048];
  {
    int4 neg = {-1,-1,-1,-1};
    int4* ip = (int4*)&idxL[tid*8];
    ip[0] = neg; ip[1] = neg;
  }
  const float4* nzp = (const float4*)noiseTab + tid*2;
  float4 nzA = nzp[0], nzB = nzp[1];
  float soc[8], V[8];
  __syncthreads();
  #pragma unroll
  for (int k=0;k<8;k++){
    float s = soc_init[tid*8+k];
    soc[k] = s;
    V[k] = interpS(tabF[0], s);
  }
  float loss = 0.0f;
  float Iprev = current[0];

  for (int t=0; t<T_STEPS; t++){
    const int cur = t & 1, nxt = cur ^ 1;
    const int tagBase = t << 13;
    float* __restrict__ sp = socP[cur];
    int*   __restrict__ il = idxL;

    // prefetch next-step table + noise into registers
    int tn = (t+1 < T_STEPS) ? t+1 : t;
    const float* tRow = TabF + (size_t)tn * FKN;
    float pf0 = tRow[tid];
    float pf1 = tRow[1024+tid];
    float pf2 = 0.0f;
    if (tid == 0) pf2 = tRow[2048];
    const float4* nzn = (const float4*)(noiseTab + (size_t)tn*N_PART) + tid*2;
    float4 nzA2 = nzn[0], nzB2 = nzn[1];

    float It = current[t];
    float vm = vmeas[t];
    float u0 = u0Tab[t];
    float coef = -(Iprev / 26267.160775850585f) * ec;
    float nz[8] = {nzA.x,nzA.y,nzA.z,nzA.w,nzB.x,nzB.y,nzB.z,nzB.w};
    const float* tf = tabF[cur];

    // ---- phase 1: propagate (vectorized socP store), then measure ----
    float s8[8];
    #pragma unroll
    for (int k=0;k<8;k++){
      float s = fmaf(V[k], coef, soc[k]);
      s = s + nz[k];
      s8[k] = __builtin_amdgcn_fmed3f(s, 1e-10f, 1.0f);  // == fminf(1,fmaxf(s,1e-10))
    }
    {
      float4 a = {s8[0],s8[1],s8[2],s8[3]}, b = {s8[4],s8[5],s8[6],s8[7]};
      float4* dst = (float4*)&sp[tid*8];
      dst[0] = a; dst[1] = b;
    }
    float dd[8];
    #pragma unroll
    for (int k=0;k<8;k++){
      float Vn = interpS(tf, s8[k]);
      V[k] = Vn;
      float d = Vn - vm;
      dd[k] = d*d;
    }
    if (strideP == 1){
      float4 a = {V[0],V[1],V[2],V[3]}, b = {V[4],V[5],V[6],V[7]};
      float4* dst = (float4*)(vHist + (size_t)t*strideT + tid*8);
      dst[0] = a; dst[1] = b;
    } else {
      #pragma unroll
      for (int k=0;k<8;k++) vHist[(size_t)t*strideT + (size_t)(tid*8+k)*strideP] = V[k];
    }

    // per-thread min fold (tree, exact) then 64-lane min via DPP (exact)
    float m01 = fminf(dd[0],dd[1]), m23 = fminf(dd[2],dd[3]);
    float m45 = fminf(dd[4],dd[5]), m67 = fminf(dd[6],dd[7]);
    float dmin = fminf(fminf(m01,m23), fminf(m45,m67));
    dmin = dppMinAll64(dmin);

    // exp prefix (wave frame; order-preserving)
    float ebase = DD2E * dmin;
    float run = 0.0f, cp[8];
    #pragma unroll
    for (int k=0;k<8;k++){
      float e = exp2f(fmaf(dd[k], -DD2E, ebase));
      run += e;
      cp[k] = run;
    }
    float sc = run;
    #pragma unroll
    for (int off=1; off<64; off<<=1){
      float o = __shfl_up(sc, (unsigned)off);
      if (lane >= off) sc += o;
    }
    float excl = __shfl_up(sc, 1);       // bitwise == prev lane's inclusive sc
    if (lane == 0) excl = 0.0f;
    if (lane == 63){ ddW[wv] = dmin; sWv[wv] = sc; }
    BAR_LGKM();                          // B1 (LDS-only ordering; vHist store overlaps)

    // commit prefetched table into the other buffer (drains during combine; read after B2(t)->phase1(t+1))
    tabF[nxt][tid]      = pf0;
    tabF[nxt][1024+tid] = pf1;
    if (tid == 0) tabF[nxt][2048] = pf2;

    // ---- combine wave stats: DPP within-16, all lanes redundant (bitwise-exact) ----
    float b0, bI, scl;
    {
      float dv = ddW[lane & 15];         // 4-lane same-addr broadcast, conflict-free
      float sw = sWv[lane & 15];
      float dG = dv;
      dG = fminf(dG, dppf<0xB1,0xf>(dG));    // quad_perm [1,0,3,2]  (xor 1)
      dG = fminf(dG, dppf<0x4E,0xf>(dG));    // quad_perm [2,3,0,1]  (xor 2)
      dG = fminf(dG, dppf<0x124,0xf>(dG));   // row_ror:4
      dG = fminf(dG, dppf<0x128,0xf>(dG));   // row_ror:8  -> 16-lane min everywhere
      float ew = exp2f(-DD2E * (dv - dG));
      float pfv = sw * ew;
      pfv += dppzf<0x111>(pfv);              // row_shr:1 (+0 fill) — bitwise == shfl_up KS
      pfv += dppzf<0x112>(pfv);              // row_shr:2
      pfv += dppzf<0x114>(pfv);              // row_shr:4
      pfv += dppzf<0x118>(pfv);              // row_shr:8
      float Sv = rdlanef(pfv, 15);
      float invS = 1.0f / Sv;
      float pfEx = dppzf<0x111>(pfv);        // lane0 -> 0 (== lane==0 fixup)
      int swv = __builtin_amdgcn_readfirstlane(wv);
      b0  = rdlanef(pfEx * invS, swv);       // exclusive block prefix, normalized
      bI  = rdlanef(pfv  * invS, swv);       // inclusive; bitwise == next wave's b0
      scl = rdlanef(ew   * invS, swv);
      if (tid == 0)
        loss = ((loss + (LOGNU - DD2LW*dG)) + logf(Sv)) - LOG8192;
    }

    // ---- slot inversion + tagged LDS scatter (bitwise-exact seams, owners only) ----
    float scl8 = scl * 8192.0f;
    float b8   = fmaf(b0, 8192.0f, -u0);       // wave base in slot units
    float bth  = fmaf(excl, scl8, b8);
    int aPrev = __float2int_rd(bth);
    if (aPrev < -1) aPrev = -1;
    #pragma unroll
    for (int k=0;k<8;k++){
      int i = tid*8 + k;
      int a;
      if (i == N_PART-1){
        a = N_PART-1;
      } else if (k == 7){
        if (lane == 63) a = __float2int_rd(fmaf(bI, 8192.0f, -u0));  // == next wave's base
        else            a = __float2int_rd(fmaf(sc, scl8, b8));      // == next thread's base
        if (a > N_PART-1) a = N_PART-1;
      } else {
        a = __float2int_rd(fmaf(cp[k], scl8, bth));
        if (a > N_PART-1) a = N_PART-1;
      }
      if (a < aPrev) a = aPrev;          // serial prefix-max (exact, fewer ops than KS)
      int st = aPrev + 1;
      if (a >= st){                              // owners only
        int tag = tagBase + i;
        atomicMax(&il[st], tag);                 // ds_max (LDS)
        for (int r = (st>>9)+1; (r<<9) <= a; ++r)
          atomicMax(&il[r<<9], tag);             // 512-region anchors
      }
      aPrev = a;
    }
    BAR_LGKM();                          // B2 (LDS-only: ds atomics + socP ordering)

    // ---- slot phase: b128 idx reads, serial prefix-max, DPP wave max-scan, gather ----
    int4 q0 = *(const int4*)&il[tid*8+0];
    int4 q1 = *(const int4*)&il[tid*8+4];
    int sl[8] = { q0.x, q0.y, q0.z, q0.w, q1.x, q1.y, q1.z, q1.w };
    int pm = sl[0];
    #pragma unroll
    for (int k=1;k<8;k++) pm = max(pm, sl[k]);
    int scn = dppMaxScan64(pm);          // inclusive across 64 lanes (exact)
    int ex = __shfl_up(scn, 1);
    if (lane == 0) ex = -1;              // wave-chunk start covered by 512-anchor
    float sn[8];
    int run2 = ex;
    #pragma unroll
    for (int k=0;k<8;k++){
      run2 = max(run2, sl[k]);           // serial prefix-max (exact)
      int idx = (run2 - tagBase) & (N_PART-1);   // proven in [0,8191]; AND = cheap insurance
      sn[k] = sp[idx];
    }
    if (strideP == 1){
      float4 a = {sn[0],sn[1],sn[2],sn[3]}, b = {sn[4],sn[5],sn[6],sn[7]};
      float4* dst = (float4*)(sHist + (size_t)t*strideT + tid*8);
      dst[0] = a; dst[1] = b;
    } else {
      #pragma unroll
      for (int k=0;k<8;k++) sHist[(size_t)t*strideT + (size_t)(tid*8+k)*strideP] = sn[k];
    }
    #pragma unroll
    for (int k=0;k<8;k++) soc[k] = sn[k];
    Iprev = It;
    nzA = nzA2; nzB = nzB2;
    // no B3: next step writes socP[nxt]; idxL read(t) completes before B1(t+1)
    // (BAR_LGKM drains lgkm), scatter(t+1) writes after B1(t+1) -> no WAR race.
  }
  if (tid == 0) lossOut[0] = loss;
}

// ---------------- kernel 6: (T,N) -> (N,T) transpose ----------------
__global__ void k_transpose(const float* __restrict__ vS, const float* __restrict__ sS,
                            float* __restrict__ outV, float* __restrict__ outS){
  __shared__ float tile[32][33];
  const float* src = blockIdx.z ? sS : vS;
  float* dst = blockIdx.z ? outS : outV;
  int t0 = blockIdx.x*32, n0 = blockIdx.y*32;
  int tx = threadIdx.x, ty = threadIdx.y;
  #pragma unroll
  for (int r=0;r<4;r++)
    tile[ty+8*r][tx] = src[(size_t)(t0+ty+8*r)*N_PART + n0 + tx];
  __syncthreads();
  #pragma unroll
  for (int r=0;r<4;r++)
    dst[(size_t)(n0+ty+8*r)*T_STEPS + t0 + tx] = tile[tx][ty+8*r];
}

extern "C" void kernel_launch(void* const* d_in, const int* in_sizes, int n_in,
                              void* d_out, int out_size, void* d_ws, size_t ws_size,
                              hipStream_t stream){
  const float* soc_init = (const float*)d_in[0];
  const float* current  = (const float*)d_in[1];
  const float* vmeas    = (const float*)d_in[2];
  const float* W1 = (const float*)d_in[3];
  const float* b1 = (const float*)d_in[4];
  const float* W2 = (const float*)d_in[5];
  const float* b2 = (const float*)d_in[6];
  const float* W3 = (const float*)d_in[7];
  const float* b3 = (const float*)d_in[8];
  const float* Ec = (const float*)d_in[9];

  float* outLoss = (float*)d_out;
  float* outV = outLoss + 1;
  float* outS = outV + (size_t)N_PART*T_STEPS;

  char* p = (char*)d_ws;
  auto carve = [&](size_t bytes)->char*{ char* r = p; p += (bytes + 255) & ~(size_t)255; return r; };
  uint32_t* knKeys  = (uint32_t*)carve((size_t)2*T_STEPS*4);
  float* u0Tab      = (float*)carve((size_t)T_STEPS*4);
  float* Zpart      = (float*)carve((size_t)4*M2TOT*4);
  float* Z2D        = (float*)carve((size_t)M2TOT*4);
  float* Gtab       = (float*)carve((size_t)T_STEPS*UKNOTS*4);
  float* TabF       = (float*)carve((size_t)T_STEPS*FKN*4);
  float* noiseTab   = (float*)carve((size_t)N_PART*T_STEPS*4);
  float* vS         = (float*)carve((size_t)N_PART*T_STEPS*4);
  float* sS         = (float*)carve((size_t)N_PART*T_STEPS*4);
  bool useScratch   = ((size_t)(p - (char*)d_ws) <= ws_size);

  k_keys<<<dim3((T_STEPS+255)/256), dim3(256), 0, stream>>>(knKeys, u0Tab);
  k_noise<<<dim3(T_STEPS), dim3(256), 0, stream>>>(knKeys, noiseTab);
  k_gemm<<<dim3((M2TOT+63)/64, 4), dim3(256), 0, stream>>>(W1, b1, W2, b2, W3, Zpart);
  k_tabZ<<<dim3((M2TOT+255)/256), dim3(256), 0, stream>>>(Zpart, b3, Z2D);
  k_tabG<<<dim3((T_STEPS*UKNOTS+255)/256), dim3(256), 0, stream>>>(Z2D, current, Gtab);
  k_tabFine<<<dim3((T_STEPS*FKN+255)/256), dim3(256), 0, stream>>>(Gtab, TabF);

  if (useScratch){
    k_filter<<<dim3(1), dim3(1024), 0, stream>>>(soc_init, current, vmeas, Ec, TabF, noiseTab,
                                                 u0Tab, vS, sS, (long)N_PART, 1L, outLoss);
    k_transpose<<<dim3(T_STEPS/32, N_PART/32, 2), dim3(32,8), 0, stream>>>(vS, sS, outV, outS);
  } else {
    k_filter<<<dim3(1), dim3(1024), 0, stream>>>(soc_init, current, vmeas, Ec, TabF, noiseTab,
                                                 u0Tab, outV, outS, 1L, (long)T_STEPS, outLoss);
  }
}

// Round 7
// 4884.038 us; speedup vs baseline: 1.3735x; 1.0155x over previous
//
#include <hip/hip_runtime.h>
#include <stdint.h>
#include <math.h>

#define N_PART 8192
#define T_STEPS 1024
#define UKNOTS 130            // coarse u-knots k=0..129, u=k/128 (cubic source grid)
#define SIKNOTS 68            // sI-knots j=0..67, sI = SI_LO + j*SI_H
#define M2TOT (UKNOTS*SIKNOTS)
#define FKN 2049              // fine linear grid in u: entries c=0..2048, u=c/2048
#define SI_LO 0.49375f
#define SI_H  0.00625f
#define LOGNU 3.6862316527834183f
#define LOG8192 9.010913347279288f
#define DD2LW 5000.0f                 // lw = LOGNU - 5000*dd, dd=(V-vm)^2
#define DD2E  7213.4752044448170f     // 5000*log2(e)

// LDS-only barrier: orders ds ops without draining outstanding global stores.
#define BAR_LGKM() asm volatile("s_waitcnt lgkmcnt(0)\n\ts_barrier" ::: "memory")

// ---- DPP helpers ----
// old=x, bound_ctrl=false: invalid lanes keep x -> identity for min/max.
template<int CTRL, int RM>
__device__ __forceinline__ int dppi(int x){
  return __builtin_amdgcn_update_dpp(x, x, CTRL, RM, 0xf, false);
}
template<int CTRL, int RM>
__device__ __forceinline__ float dppf(float x){
  return __int_as_float(__builtin_amdgcn_update_dpp(__float_as_int(x), __float_as_int(x), CTRL, RM, 0xf, false));
}
// bound_ctrl=true: invalid lanes produce 0 -> "+0"/max-identity fill.
// CTRL=0x138 (wave_shr:1) shifts the WHOLE wave by 1 lane (crosses row
// boundaries, unlike row_shr) -> bitwise == __shfl_up(x,1) with 0-fill at lane0.
template<int CTRL>
__device__ __forceinline__ float dppzf(float x){
  return __int_as_float(__builtin_amdgcn_update_dpp(0, __float_as_int(x), CTRL, 0xf, 0xf, true));
}
template<int CTRL>
__device__ __forceinline__ int dppzi(int x){
  return __builtin_amdgcn_update_dpp(0, x, CTRL, 0xf, 0xf, true);
}
__device__ __forceinline__ float rdlanef(float x, int l){
  return __int_as_float(__builtin_amdgcn_readlane(__float_as_int(x), l));
}
// 64-lane inclusive max-scan: row_shr 1/2/4/8 then row_bcast15 (rows1,3) + row_bcast31 (rows2,3)
__device__ __forceinline__ int dppMaxScan64(int x){
  x = max(x, dppi<0x111,0xf>(x));
  x = max(x, dppi<0x112,0xf>(x));
  x = max(x, dppi<0x114,0xf>(x));
  x = max(x, dppi<0x118,0xf>(x));
  x = max(x, dppi<0x142,0xa>(x));
  x = max(x, dppi<0x143,0xc>(x));
  return x;
}
// 64-lane min-reduce (exact): prefix-min scan, total lands in lane 63, broadcast via readlane
__device__ __forceinline__ float dppMinAll64(float x){
  x = fminf(x, dppf<0x111,0xf>(x));
  x = fminf(x, dppf<0x112,0xf>(x));
  x = fminf(x, dppf<0x114,0xf>(x));
  x = fminf(x, dppf<0x118,0xf>(x));
  x = fminf(x, dppf<0x142,0xa>(x));
  x = fminf(x, dppf<0x143,0xc>(x));
  return __int_as_float(__builtin_amdgcn_readlane(__float_as_int(x), 63));
}

// ---------------- Threefry-2x32 (exact JAX semantics) ----------------
__device__ __forceinline__ uint32_t rotl32(uint32_t x, int d){ return (x<<d)|(x>>(32-d)); }

__device__ __forceinline__ void tf2x32(uint32_t k0, uint32_t k1, uint32_t c0, uint32_t c1,
                                       uint32_t& o0, uint32_t& o1){
  uint32_t ks2 = k0 ^ k1 ^ 0x1BD11BDAu;
  uint32_t x0 = c0 + k0, x1 = c1 + k1;
  #define TFR(r) { x0 += x1; x1 = rotl32(x1, r); x1 ^= x0; }
  TFR(13) TFR(15) TFR(26) TFR(6)
  x0 += k1;  x1 += ks2 + 1u;
  TFR(17) TFR(29) TFR(16) TFR(24)
  x0 += ks2; x1 += k0 + 2u;
  TFR(13) TFR(15) TFR(26) TFR(6)
  x0 += k0;  x1 += k1 + 3u;
  TFR(17) TFR(29) TFR(16) TFR(24)
  x0 += k1;  x1 += ks2 + 4u;
  TFR(13) TFR(15) TFR(26) TFR(6)
  x0 += ks2; x1 += k0 + 5u;
  #undef TFR
  o0 = x0; o1 = x1;
}

__device__ __forceinline__ float erfinv_xla(float x){
  float w = -log1pf(-x*x);
  float p;
  if (w < 5.0f){
    w -= 2.5f;
    p = 2.81022636e-08f;
    p = fmaf(p, w, 3.43273939e-07f);
    p = fmaf(p, w, -3.5233877e-06f);
    p = fmaf(p, w, -4.39150654e-06f);
    p = fmaf(p, w, 0.00021858087f);
    p = fmaf(p, w, -0.00125372503f);
    p = fmaf(p, w, -0.00417768164f);
    p = fmaf(p, w, 0.246640727f);
    p = fmaf(p, w, 1.50140941f);
  } else {
    w = sqrtf(w) - 3.0f;
    p = -0.000200214257f;
    p = fmaf(p, w, 0.000100950558f);
    p = fmaf(p, w, 0.00134934322f);
    p = fmaf(p, w, -0.00367342844f);
    p = fmaf(p, w, 0.00573950773f);
    p = fmaf(p, w, -0.0076224613f);
    p = fmaf(p, w, 0.00943887047f);
    p = fmaf(p, w, 1.00167406f);
    p = fmaf(p, w, 2.83297682f);
  }
  return p * x;
}

// ---------------- kernel 1: per-step keys + u0 ----------------
__global__ void k_keys(uint32_t* __restrict__ knKeys, float* __restrict__ u0Tab){
  int t = blockIdx.x*blockDim.x + threadIdx.x;
  if (t >= T_STEPS) return;
  uint32_t kA0,kA1,kB0,kB1;
  tf2x32(0u,42u, 0u,0u, kA0,kA1);
  tf2x32(0u,42u, 0u,1u, kB0,kB1);
  auto splitElem = [&](uint32_t kk0, uint32_t kk1, int idx)->uint32_t{
    uint32_t o0,o1;
    if (idx < T_STEPS){ tf2x32(kk0,kk1,(uint32_t)idx,(uint32_t)(T_STEPS+idx),o0,o1); return o0; }
    int i = idx - T_STEPS;
    tf2x32(kk0,kk1,(uint32_t)i,(uint32_t)(T_STEPS+i),o0,o1); return o1;
  };
  uint32_t n0 = splitElem(kA0,kA1, 2*t);
  uint32_t n1 = splitElem(kA0,kA1, 2*t+1);
  uint32_t r0 = splitElem(kB0,kB1, 2*t);
  uint32_t r1 = splitElem(kB0,kB1, 2*t+1);
  knKeys[2*t] = n0; knKeys[2*t+1] = n1;
  uint32_t o0,o1; tf2x32(r0,r1,0u,0u,o0,o1);
  u0Tab[t] = __uint_as_float((o0>>9) | 0x3f800000u) - 1.0f;
}

// ---------------- kernel 2: noise table ----------------
__global__ void k_noise(const uint32_t* __restrict__ knKeys, float* __restrict__ noiseTab){
  int t = blockIdx.x;
  uint32_t k0 = knKeys[2*t], k1 = knKeys[2*t+1];
  const int half = N_PART/2;
  const float lo = -0.99999994f;
  for (int i = threadIdx.x; i < half; i += blockDim.x){
    uint32_t o0,o1; tf2x32(k0,k1,(uint32_t)i,(uint32_t)(half+i),o0,o1);
    float ua = __uint_as_float((o0>>9)|0x3f800000u) - 1.0f;
    float ub = __uint_as_float((o1>>9)|0x3f800000u) - 1.0f;
    float va = fmaxf(lo, ua*2.0f + lo);
    float vb = fmaxf(lo, ub*2.0f + lo);
    float na = 1.4142135623730951f * erfinv_xla(va);
    float nb = 1.4142135623730951f * erfinv_xla(vb);
    noiseTab[(size_t)t*N_PART + i]        = 0.005f * na;
    noiseTab[(size_t)t*N_PART + half + i] = 0.005f * nb;
  }
}

// ---------------- kernel 3: (u, sI)-grid MLP GEMM ----------------
__global__ __launch_bounds__(256) void k_gemm(
    const float* __restrict__ W1, const float* __restrict__ b1,
    const float* __restrict__ W2, const float* __restrict__ b2,
    const float* __restrict__ W3, float* __restrict__ Zpart)
{
  __shared__ float sA[32][64];
  __shared__ float sB[32][129];
  __shared__ float sSoc[64], sSI[64];
  __shared__ float sRed[64][17];

  const int tid = threadIdx.x;
  const int m0 = blockIdx.x * 64;
  const int n0 = blockIdx.y * 128;

  if (tid < 64){
    int r = m0 + tid; if (r >= M2TOT) r = M2TOT-1;
    int k = r / SIKNOTS;
    int j = r - k*SIKNOTS;
    float u = (float)k * (1.0f/128.0f);
    sSoc[tid] = u*u;
    sSI[tid]  = SI_LO + SI_H * (float)j;
  }
  __syncthreads();

  const int tx = tid & 15;
  const int ty = tid >> 4;
  float acc[4][8];
  #pragma unroll
  for (int i=0;i<4;i++)
    #pragma unroll
    for (int q=0;q<8;q++) acc[i][q] = 0.0f;

  for (int kc = 0; kc < 1024; kc += 32){
    {
      int base = tid*8;
      int jj = base >> 6;
      int mm = base & 63;
      int j = kc + jj;
      float w0 = W1[2*j], w1v = W1[2*j+1], bb = b1[j];
      #pragma unroll
      for (int e=0;e<8;e++){
        int m = mm + e;
        float pre = sSoc[m]*w0 + sSI[m]*w1v + bb;
        sA[jj][m] = 1.0f/(1.0f + expf(-pre));
      }
    }
    {
      int nl = tid & 127;
      int h  = tid >> 7;
      const float* src = W2 + (size_t)(n0 + nl)*1024 + kc + h*16;
      float4 v0 = *(const float4*)(src+0);
      float4 v1 = *(const float4*)(src+4);
      float4 v2 = *(const float4*)(src+8);
      float4 v3 = *(const float4*)(src+12);
      int kb = h*16;
      sB[kb+ 0][nl]=v0.x; sB[kb+ 1][nl]=v0.y; sB[kb+ 2][nl]=v0.z; sB[kb+ 3][nl]=v0.w;
      sB[kb+ 4][nl]=v1.x; sB[kb+ 5][nl]=v1.y; sB[kb+ 6][nl]=v1.z; sB[kb+ 7][nl]=v1.w;
      sB[kb+ 8][nl]=v2.x; sB[kb+ 9][nl]=v2.y; sB[kb+10][nl]=v2.z; sB[kb+11][nl]=v2.w;
      sB[kb+12][nl]=v3.x; sB[kb+13][nl]=v3.y; sB[kb+14][nl]=v3.z; sB[kb+15][nl]=v3.w;
    }
    __syncthreads();
    #pragma unroll
    for (int kk=0;kk<32;kk++){
      float a_[4], b_[8];
      #pragma unroll
      for (int i=0;i<4;i++) a_[i] = sA[kk][ty*4+i];
      #pragma unroll
      for (int q=0;q<8;q++) b_[q] = sB[kk][tx*8+q];
      #pragma unroll
      for (int i=0;i<4;i++)
        #pragma unroll
        for (int q=0;q<8;q++) acc[i][q] = fmaf(a_[i], b_[q], acc[i][q]);
    }
    __syncthreads();
  }
  float part[4] = {0.f,0.f,0.f,0.f};
  #pragma unroll
  for (int q=0;q<8;q++){
    int n = n0 + tx*8 + q;
    float bb = b2[n], w3 = W3[n];
    #pragma unroll
    for (int i=0;i<4;i++){
      float h = 1.0f/(1.0f + expf(-(acc[i][q] + bb)));
      part[i] = fmaf(w3, h, part[i]);
    }
  }
  #pragma unroll
  for (int i=0;i<4;i++) sRed[ty*4+i][tx] = part[i];
  __syncthreads();
  if (tid < 64){
    int r = m0 + tid;
    if (r < M2TOT){
      float s = 0.0f;
      #pragma unroll
      for (int x=0;x<16;x++) s += sRed[tid][x];
      Zpart[(size_t)blockIdx.y*M2TOT + r] = s;
    }
  }
}

// ---------------- kernel 4a: combine Z parts ----------------
__global__ void k_tabZ(const float* __restrict__ Zpart, const float* __restrict__ b3,
                       float* __restrict__ Z2D){
  int r = blockIdx.x*blockDim.x + threadIdx.x;
  if (r >= M2TOT) return;
  Z2D[r] = ((Zpart[r] + Zpart[M2TOT+r]) + Zpart[2*M2TOT+r]) + Zpart[3*M2TOT+r] + b3[0];
}

// ---------------- kernel 4b: per-(t,k) sI-interp + voc -> coarse G table ----------------
__global__ void k_tabG(const float* __restrict__ Z2D, const float* __restrict__ current,
                       float* __restrict__ Gtab){
  int m = blockIdx.x*blockDim.x + threadIdx.x;
  if (m >= T_STEPS*UKNOTS) return;
  int t = m / UKNOTS;
  int k = m - t*UKNOTS;
  float It = current[t];
  float sI = (It + 2.0f) * 0.25f;
  float x = (sI - SI_LO) * (1.0f/SI_H);
  int c = (int)x; if (c < 1) c = 1; if (c > 65) c = 65;
  float xi = x - (float)c;
  const float* zp = Z2D + k*SIKNOTS + (c-1);
  float y0 = zp[0], y1 = zp[1], y2 = zp[2], y3 = zp[3];
  float xm1 = xi - 1.0f, xm2 = xi - 2.0f, xp1 = xi + 1.0f;
  float w0 = -(1.0f/6.0f) * xi  * xm1 * xm2;
  float w1 =  0.5f        * xp1 * xm1 * xm2;
  float w2 = -0.5f        * xi  * xp1 * xm2;
  float w3 =  (1.0f/6.0f) * xi  * xp1 * xm1;
  float z = ((w0*y0 + w1*y1) + w2*y2) + w3*y3;
  double u = (double)k / 128.0;
  double s = u*u;
  const double vL=-1.59614486, v0=4.13646328, gam=0.63726463, alp=1.40174122, bet=2.54478965;
  double voc = vL + (v0-vL)*exp(gam*(s-1.0)) + alp*vL*(s-1.0)
             + (1.0-alp)*vL*(exp(-bet) - exp(-bet*sqrt(s)));
  Gtab[m] = (float)voc - It*z;
}

// ---------------- kernel 4c: coarse cubic -> fine scalar table ----------------
__device__ __forceinline__ float cubicEval(const float* __restrict__ g, int cf){
  float x = (float)cf * (1.0f/16.0f);
  int cc = (int)x; if (cc > 127) cc = 127;
  float xi = x - (float)cc;
  float y0 = (cc == 0) ? g[1] : g[cc-1];   // even mirror in u
  float y1 = g[cc], y2 = g[cc+1], y3 = g[cc+2];
  float xm1 = xi - 1.0f, xm2 = xi - 2.0f, xp1 = xi + 1.0f;
  float w0 = -(1.0f/6.0f) * xi  * xm1 * xm2;
  float w1 =  0.5f        * xp1 * xm1 * xm2;
  float w2 = -0.5f        * xi  * xp1 * xm2;
  float w3 =  (1.0f/6.0f) * xi  * xp1 * xm1;
  return ((w0*y0 + w1*y1) + w2*y2) + w3*y3;
}
__global__ void k_tabFine(const float* __restrict__ Gtab, float* __restrict__ TabF){
  int m = blockIdx.x*blockDim.x + threadIdx.x;
  if (m >= T_STEPS*FKN) return;
  int t = m / FKN;
  int c = m - t*FKN;
  TabF[m] = cubicEval(Gtab + t*UKNOTS, c);
}

// linear interp on scalar fine table (LDS)
__device__ __forceinline__ float interpS(const float* __restrict__ tab, float s){
  float x = sqrtf(s) * 2048.0f;
  float cf = floorf(x);
  cf = fminf(cf, 2047.0f);
  int c = (int)cf;
  float xi = x - cf;
  float y0 = tab[c], y1 = tab[c+1];
  return fmaf(xi, y1 - y0, y0);
}

// ---------------- kernel 5: sequential particle filter (single block, 1024 thr) ----------------
// Isolated changes this round (DS-trim; all bitwise-exact):
//  1. KS float-scan offset-1 step via DPP wave_shr:1 zero-fill (crosses row
//     boundaries unlike row_shr) — operand bitwise == __shfl_up(sc,1); lane0
//     adds +0.0 to a positive value. 1 bpermute removed.
//  2. excl via wave_shr:1 zero-fill — lane0 = 0.0 IS the fixup. 1 bpermute removed.
//  3. slot-phase ex via wave_shr:1 zero-fill — lane0 = 0 instead of -1; exact
//     because sl[0] at lane0 slots (wv*512) always holds a current tag >= 0
//     (owner-st write or 512-anchor; partition covers every slot), so
//     max(0,sl[0]) == max(-1,sl[0]). 1 bpermute removed.
//  4. ddW/sWv packed into float2 ddsw[16]: 1 ds_write_b64 (lane63) + 1
//     ds_read_b64 (combine) instead of 2+2 b32 ops.
__global__ __launch_bounds__(1024) void k_filter(
    const float* __restrict__ soc_init, const float* __restrict__ current,
    const float* __restrict__ vmeas,   const float* __restrict__ Ecrit,
    const float* __restrict__ TabF,    const float* __restrict__ noiseTab,
    const float* __restrict__ u0Tab,
    float* __restrict__ vHist, float* __restrict__ sHist,
    long strideT, long strideP, float* __restrict__ lossOut)
{
  __shared__ __align__(16) float socP[2][N_PART];  // 64 KiB dbuf (exact f32 state)
  __shared__ __align__(16) float tabF[2][2052];    // 16.4 KiB dbuf
  __shared__ __align__(16) int   idxL[N_PART];     // 32 KiB resample tags (single buf)
  __shared__ __align__(8)  float2 ddsw[16];        // {dmin, scTotal} per wave

  const int tid = threadIdx.x;
  const int lane = tid & 63;
  const int wv = tid >> 6;
  const float ec = Ecrit[0];

  // prologue
  tabF[0][tid]      = TabF[tid];
  tabF[0][1024+tid] = TabF[1024+tid];
  if (tid == 0) tabF[0][2048] = TabF[2048];
  {
    int4 neg = {-1,-1,-1,-1};
    int4* ip = (int4*)&idxL[tid*8];
    ip[0] = neg; ip[1] = neg;
  }
  const float4* nzp = (const float4*)noiseTab + tid*2;
  float4 nzA = nzp[0], nzB = nzp[1];
  float soc[8], V[8];
  __syncthreads();
  #pragma unroll
  for (int k=0;k<8;k++){
    float s = soc_init[tid*8+k];
    soc[k] = s;
    V[k] = interpS(tabF[0], s);
  }
  float loss = 0.0f;
  float Iprev = current[0];

  for (int t=0; t<T_STEPS; t++){
    const int cur = t & 1, nxt = cur ^ 1;
    const int tagBase = t << 13;
    float* __restrict__ sp = socP[cur];
    int*   __restrict__ il = idxL;

    // prefetch next-step table + noise into registers
    int tn = (t+1 < T_STEPS) ? t+1 : t;
    const float* tRow = TabF + (size_t)tn * FKN;
    float pf0 = tRow[tid];
    float pf1 = tRow[1024+tid];
    float pf2 = 0.0f;
    if (tid == 0) pf2 = tRow[2048];
    const float4* nzn = (const float4*)(noiseTab + (size_t)tn*N_PART) + tid*2;
    float4 nzA2 = nzn[0], nzB2 = nzn[1];

    float It = current[t];
    float vm = vmeas[t];
    float u0 = u0Tab[t];
    float coef = -(Iprev / 26267.160775850585f) * ec;
    float nz[8] = {nzA.x,nzA.y,nzA.z,nzA.w,nzB.x,nzB.y,nzB.z,nzB.w};
    const float* tf = tabF[cur];

    // ---- phase 1: propagate (vectorized socP store), then measure ----
    float s8[8];
    #pragma unroll
    for (int k=0;k<8;k++){
      float s = fmaf(V[k], coef, soc[k]);
      s = s + nz[k];
      s8[k] = __builtin_amdgcn_fmed3f(s, 1e-10f, 1.0f);  // == fminf(1,fmaxf(s,1e-10))
    }
    {
      float4 a = {s8[0],s8[1],s8[2],s8[3]}, b = {s8[4],s8[5],s8[6],s8[7]};
      float4* dst = (float4*)&sp[tid*8];
      dst[0] = a; dst[1] = b;
    }
    float dd[8];
    #pragma unroll
    for (int k=0;k<8;k++){
      float Vn = interpS(tf, s8[k]);
      V[k] = Vn;
      float d = Vn - vm;
      dd[k] = d*d;
    }
    if (strideP == 1){
      float4 a = {V[0],V[1],V[2],V[3]}, b = {V[4],V[5],V[6],V[7]};
      float4* dst = (float4*)(vHist + (size_t)t*strideT + tid*8);
      dst[0] = a; dst[1] = b;
    } else {
      #pragma unroll
      for (int k=0;k<8;k++) vHist[(size_t)t*strideT + (size_t)(tid*8+k)*strideP] = V[k];
    }

    // per-thread min fold (tree, exact) then 64-lane min via DPP (exact)
    float m01 = fminf(dd[0],dd[1]), m23 = fminf(dd[2],dd[3]);
    float m45 = fminf(dd[4],dd[5]), m67 = fminf(dd[6],dd[7]);
    float dmin = fminf(fminf(m01,m23), fminf(m45,m67));
    dmin = dppMinAll64(dmin);

    // exp prefix (wave frame; order-preserving)
    float ebase = DD2E * dmin;
    float run = 0.0f, cp[8];
    #pragma unroll
    for (int k=0;k<8;k++){
      float e = exp2f(fmaf(dd[k], -DD2E, ebase));
      run += e;
      cp[k] = run;
    }
    float sc = run;
    sc += dppzf<0x138>(sc);              // KS offset 1 via wave_shr:1 (lane0 += 0.0)
    #pragma unroll
    for (int off=2; off<64; off<<=1){    // offsets 2,4,8,16,32 (cross-row, exact KS)
      float o = __shfl_up(sc, (unsigned)off);
      if (lane >= off) sc += o;
    }
    float excl = dppzf<0x138>(sc);       // prev lane's inclusive sc; lane0 = 0.0 (exact)
    if (lane == 63) ddsw[wv] = make_float2(dmin, sc);
    BAR_LGKM();                          // B1 (LDS-only ordering; vHist store overlaps)

    // commit prefetched table into the other buffer (drains during combine; read after B2(t)->phase1(t+1))
    tabF[nxt][tid]      = pf0;
    tabF[nxt][1024+tid] = pf1;
    if (tid == 0) tabF[nxt][2048] = pf2;

    // ---- combine wave stats: DPP within-16, all lanes redundant (bitwise-exact) ----
    float b0, bI, scl;
    {
      float2 dsw = ddsw[lane & 15];      // 4-lane same-addr broadcast, conflict-free
      float dv = dsw.x;
      float sw = dsw.y;
      float dG = dv;
      dG = fminf(dG, dppf<0xB1,0xf>(dG));    // quad_perm [1,0,3,2]  (xor 1)
      dG = fminf(dG, dppf<0x4E,0xf>(dG));    // quad_perm [2,3,0,1]  (xor 2)
      dG = fminf(dG, dppf<0x124,0xf>(dG));   // row_ror:4
      dG = fminf(dG, dppf<0x128,0xf>(dG));   // row_ror:8  -> 16-lane min everywhere
      float ew = exp2f(-DD2E * (dv - dG));
      float pfv = sw * ew;
      pfv += dppzf<0x111>(pfv);              // row_shr:1 (+0 fill) — bitwise == shfl_up KS
      pfv += dppzf<0x112>(pfv);              // row_shr:2
      pfv += dppzf<0x114>(pfv);              // row_shr:4
      pfv += dppzf<0x118>(pfv);              // row_shr:8
      float Sv = rdlanef(pfv, 15);
      float invS = 1.0f / Sv;
      float pfEx = dppzf<0x111>(pfv);        // lane0 -> 0 (== lane==0 fixup)
      int swv = __builtin_amdgcn_readfirstlane(wv);
      b0  = rdlanef(pfEx * invS, swv);       // exclusive block prefix, normalized
      bI  = rdlanef(pfv  * invS, swv);       // inclusive; bitwise == next wave's b0
      scl = rdlanef(ew   * invS, swv);
      if (tid == 0)
        loss = ((loss + (LOGNU - DD2LW*dG)) + logf(Sv)) - LOG8192;
    }

    // ---- slot inversion + tagged LDS scatter (bitwise-exact seams, owners only) ----
    float scl8 = scl * 8192.0f;
    float b8   = fmaf(b0, 8192.0f, -u0);       // wave base in slot units
    float bth  = fmaf(excl, scl8, b8);
    int aPrev = __float2int_rd(bth);
    if (aPrev < -1) aPrev = -1;
    #pragma unroll
    for (int k=0;k<8;k++){
      int i = tid*8 + k;
      int a;
      if (i == N_PART-1){
        a = N_PART-1;
      } else if (k == 7){
        if (lane == 63) a = __float2int_rd(fmaf(bI, 8192.0f, -u0));  // == next wave's base
        else            a = __float2int_rd(fmaf(sc, scl8, b8));      // == next thread's base
        if (a > N_PART-1) a = N_PART-1;
      } else {
        a = __float2int_rd(fmaf(cp[k], scl8, bth));
        if (a > N_PART-1) a = N_PART-1;
      }
      if (a < aPrev) a = aPrev;          // serial prefix-max (exact)
      int st = aPrev + 1;
      if (a >= st){                              // owners only
        int tag = tagBase + i;
        atomicMax(&il[st], tag);                 // ds_max (LDS)
        for (int r = (st>>9)+1; (r<<9) <= a; ++r)
          atomicMax(&il[r<<9], tag);             // 512-region anchors
      }
      aPrev = a;
    }
    BAR_LGKM();                          // B2 (LDS-only: ds atomics + socP ordering)

    // ---- slot phase: b128 idx reads, serial prefix-max, DPP wave max-scan, gather ----
    int4 q0 = *(const int4*)&il[tid*8+0];
    int4 q1 = *(const int4*)&il[tid*8+4];
    int sl[8] = { q0.x, q0.y, q0.z, q0.w, q1.x, q1.y, q1.z, q1.w };
    int pm = sl[0];
    #pragma unroll
    for (int k=1;k<8;k++) pm = max(pm, sl[k]);
    int scn = dppMaxScan64(pm);          // inclusive across 64 lanes (exact)
    int ex = dppzi<0x138>(scn);          // wave_shr:1, lane0 = 0 (exact: sl[0] >= 0 always,
                                         // lane0 slot wv*512 carries a current tag)
    float sn[8];
    int run2 = ex;
    #pragma unroll
    for (int k=0;k<8;k++){
      run2 = max(run2, sl[k]);           // serial prefix-max (exact)
      int idx = (run2 - tagBase) & (N_PART-1);   // proven in [0,8191]; AND = cheap insurance
      sn[k] = sp[idx];
    }
    if (strideP == 1){
      float4 a = {sn[0],sn[1],sn[2],sn[3]}, b = {sn[4],sn[5],sn[6],sn[7]};
      float4* dst = (float4*)(sHist + (size_t)t*strideT + tid*8);
      dst[0] = a; dst[1] = b;
    } else {
      #pragma unroll
      for (int k=0;k<8;k++) sHist[(size_t)t*strideT + (size_t)(tid*8+k)*strideP] = sn[k];
    }
    #pragma unroll
    for (int k=0;k<8;k++) soc[k] = sn[k];
    Iprev = It;
    nzA = nzA2; nzB = nzB2;
    // no B3: next step writes socP[nxt]; idxL read(t) completes before B1(t+1)
    // (BAR_LGKM drains lgkm), scatter(t+1) writes after B1(t+1) -> no WAR race.
  }
  if (tid == 0) lossOut[0] = loss;
}

// ---------------- kernel 6: (T,N) -> (N,T) transpose ----------------
__global__ void k_transpose(const float* __restrict__ vS, const float* __restrict__ sS,
                            float* __restrict__ outV, float* __restrict__ outS){
  __shared__ float tile[32][33];
  const float* src = blockIdx.z ? sS : vS;
  float* dst = blockIdx.z ? outS : outV;
  int t0 = blockIdx.x*32, n0 = blockIdx.y*32;
  int tx = threadIdx.x, ty = threadIdx.y;
  #pragma unroll
  for (int r=0;r<4;r++)
    tile[ty+8*r][tx] = src[(size_t)(t0+ty+8*r)*N_PART + n0 + tx];
  __syncthreads();
  #pragma unroll
  for (int r=0;r<4;r++)
    dst[(size_t)(n0+ty+8*r)*T_STEPS + t0 + tx] = tile[tx][ty+8*r];
}

extern "C" void kernel_launch(void* const* d_in, const int* in_sizes, int n_in,
                              void* d_out, int out_size, void* d_ws, size_t ws_size,
                              hipStream_t stream){
  const float* soc_init = (const float*)d_in[0];
  const float* current  = (const float*)d_in[1];
  const float* vmeas    = (const float*)d_in[2];
  const float* W1 = (const float*)d_in[3];
  const float* b1 = (const float*)d_in[4];
  const float* W2 = (const float*)d_in[5];
  const float* b2 = (const float*)d_in[6];
  const float* W3 = (const float*)d_in[7];
  const float* b3 = (const float*)d_in[8];
  const float* Ec = (const float*)d_in[9];

  float* outLoss = (float*)d_out;
  float* outV = outLoss + 1;
  float* outS = outV + (size_t)N_PART*T_STEPS;

  char* p = (char*)d_ws;
  auto carve = [&](size_t bytes)->char*{ char* r = p; p += (bytes + 255) & ~(size_t)255; return r; };
  uint32_t* knKeys  = (uint32_t*)carve((size_t)2*T_STEPS*4);
  float* u0Tab      = (float*)carve((size_t)T_STEPS*4);
  float* Zpart      = (float*)carve((size_t)4*M2TOT*4);
  float* Z2D        = (float*)carve((size_t)M2TOT*4);
  float* Gtab       = (float*)carve((size_t)T_STEPS*UKNOTS*4);
  float* TabF       = (float*)carve((size_t)T_STEPS*FKN*4);
  float* noiseTab   = (float*)carve((size_t)N_PART*T_STEPS*4);
  float* vS         = (float*)carve((size_t)N_PART*T_STEPS*4);
  float* sS         = (float*)carve((size_t)N_PART*T_STEPS*4);
  bool useScratch   = ((size_t)(p - (char*)d_ws) <= ws_size);

  k_keys<<<dim3((T_STEPS+255)/256), dim3(256), 0, stream>>>(knKeys, u0Tab);
  k_noise<<<dim3(T_STEPS), dim3(256), 0, stream>>>(knKeys, noiseTab);
  k_gemm<<<dim3((M2TOT+63)/64, 4), dim3(256), 0, stream>>>(W1, b1, W2, b2, W3, Zpart);
  k_tabZ<<<dim3((M2TOT+255)/256), dim3(256), 0, stream>>>(Zpart, b3, Z2D);
  k_tabG<<<dim3((T_STEPS*UKNOTS+255)/256), dim3(256), 0, stream>>>(Z2D, current, Gtab);
  k_tabFine<<<dim3((T_STEPS*FKN+255)/256), dim3(256), 0, stream>>>(Gtab, TabF);

  if (useScratch){
    k_filter<<<dim3(1), dim3(1024), 0, stream>>>(soc_init, current, vmeas, Ec, TabF, noiseTab,
                                                 u0Tab, vS, sS, (long)N_PART, 1L, outLoss);
    k_transpose<<<dim3(T_STEPS/32, N_PART/32, 2), dim3(32,8), 0, stream>>>(vS, sS, outV, outS);
  } else {
    k_filter<<<dim3(1), dim3(1024), 0, stream>>>(soc_init, current, vmeas, Ec, TabF, noiseTab,
                                                 u0Tab, outV, outS, 1L, (long)T_STEPS, outLoss);
  }
}